// Round 5
// baseline (757.431 us; speedup 1.0000x reference)
//
#include <hip/hip_runtime.h>

typedef __bf16 bf16x8 __attribute__((ext_vector_type(8)));
typedef __bf16 bf16x4 __attribute__((ext_vector_type(4)));
typedef float f32x4 __attribute__((ext_vector_type(4)));
typedef unsigned short u16x8 __attribute__((ext_vector_type(8)));
typedef unsigned short u16x4 __attribute__((ext_vector_type(4)));

__device__ __forceinline__ unsigned short f2b(float f) {
    union { float f; unsigned int u; } v; v.f = f;
    unsigned int r = v.u + 0x7fffu + ((v.u >> 16) & 1u);
    return (unsigned short)(r >> 16);
}
__device__ __forceinline__ float b2f(unsigned short b) {
    union { unsigned int u; float f; } v; v.u = ((unsigned int)b) << 16;
    return v.f;
}

__device__ __forceinline__ void gll16(const unsigned short* g, unsigned short* l) {
    __builtin_amdgcn_global_load_lds(
        (const __attribute__((address_space(1))) unsigned int*)g,
        (__attribute__((address_space(3))) unsigned int*)l, 16, 0, 0);
}

// ---------------- weight transpose + bf16 convert: W[K][NN] -> Wt[NN][K] ----------------
__global__ __launch_bounds__(256) void transpose_to_bf16(
    const float* __restrict__ W, unsigned short* __restrict__ Wt, int K, int NN)
{
    __shared__ float tile[32][33];
    int k0 = blockIdx.x * 32, n0 = blockIdx.y * 32;
    int tx = threadIdx.x & 31, ty = threadIdx.x >> 5;
    for (int r = ty; r < 32; r += 8)
        tile[r][tx] = W[(size_t)(k0 + r) * NN + n0 + tx];
    __syncthreads();
    for (int r = ty; r < 32; r += 8)
        Wt[(size_t)(n0 + r) * K + k0 + tx] = f2b(tile[tx][r]);
}

// ---------------- per-layer Q/K/V weight transpose ----------------
__global__ __launch_bounds__(256) void prep_wT(
    const float* __restrict__ Wq, const float* __restrict__ Wk, const float* __restrict__ Wv,
    unsigned short* __restrict__ wT)
{
    int l = blockIdx.x / 3, w = blockIdx.x % 3;
    const float* src = (w == 0 ? Wq : w == 1 ? Wk : Wv) + (size_t)l * 1024;
    unsigned short* dst = wT + ((size_t)l * 3 + w) * 1024;
    float scale = (w == 0) ? 0.0625f : 1.0f;
    int t = threadIdx.x;
    f32x4 v = *(const f32x4*)&src[t * 4];
    int d = (t * 4) >> 5, j0 = (t * 4) & 31;
    #pragma unroll
    for (int e = 0; e < 4; e++)
        dst[(j0 + e) * 32 + d] = f2b(v[e] * scale);
}

// ---------------- pe = x + pos_emb[positions] -> bf16 ----------------
__global__ __launch_bounds__(256) void add_posemb(
    const float* __restrict__ x, const int* __restrict__ pos,
    const float* __restrict__ pe, unsigned short* __restrict__ cur)
{
    size_t row = blockIdx.x;
    int t = threadIdx.x;
    int p = pos[row];
    float v = x[row * 256 + t] + pe[(size_t)p * 256 + t];
    cur[row * 256 + t] = f2b(v);
}

__global__ __launch_bounds__(256) void to_bf16_kernel(
    const float* __restrict__ in, unsigned short* __restrict__ o, int n)
{
    int i = blockIdx.x * 256 + threadIdx.x;
    int stride = gridDim.x * 256;
    for (; i < n; i += stride) o[i] = f2b(in[i]);
}

// ---------------- fused attention per (n,h): projections + softmax(QK^T)V ----------------
__global__ __launch_bounds__(384, 2) void attn_kernel(
    const unsigned short* __restrict__ cur, const unsigned short* __restrict__ qb,
    const unsigned short* __restrict__ wT,
    unsigned short* __restrict__ og)
{
    __shared__ __align__(16) unsigned short smem[96 * 104 + 96 * 32];
    unsigned short* qs = smem;             // [96][40]
    unsigned short* ks = smem + 96 * 40;   // [96][40]
    unsigned short* ps = smem;             // [96][104]  (valid after barrier 2)
    unsigned short* vs = smem + 96 * 104;  // V subtiled

    int nh = blockIdx.x;
    int n = nh >> 3, h = nh & 7;
    int tid = threadIdx.x;
    int wave = tid >> 6, lane = tid & 63;
    int lr = lane & 15, lg = lane >> 4;
    int hiw = lane & 1;

    bf16x8 wq[2], wk[2], wv[2];
    #pragma unroll
    for (int ct = 0; ct < 2; ct++) {
        int o = (ct * 16 + lr) * 32 + lg * 8;
        wq[ct] = *(const bf16x8*)&wT[o];
        wk[ct] = *(const bf16x8*)&wT[1024 + o];
        wv[ct] = *(const bf16x8*)&wT[2048 + o];
    }

    {
        int tile = wave;
        int row = tile * 16 + lr;
        bf16x8 aq = {0,0,0,0,0,0,0,0}, ac = {0,0,0,0,0,0,0,0};
        if (row < 90) {
            size_t base = ((size_t)(n * 90 + row)) * 256 + h * 32 + lg * 8;
            aq = *(const bf16x8*)&qb[base];
            ac = *(const bf16x8*)&cur[base];
        }
        f32x4 zz = {0.f, 0.f, 0.f, 0.f};
        #pragma unroll
        for (int ct = 0; ct < 2; ct++) {
            f32x4 qc = __builtin_amdgcn_mfma_f32_16x16x32_bf16(aq, wq[ct], zz, 0, 0, 0);
            f32x4 kc = __builtin_amdgcn_mfma_f32_16x16x32_bf16(ac, wk[ct], zz, 0, 0, 0);
            f32x4 vc = __builtin_amdgcn_mfma_f32_16x16x32_bf16(ac, wv[ct], zz, 0, 0, 0);
            #pragma unroll
            for (int rr = 0; rr < 4; rr++) {
                float oq = __shfl_xor(qc[rr], 1);
                unsigned a16 = f2b(qc[rr]), o16 = f2b(oq);
                unsigned pk = hiw ? (o16 | (a16 << 16)) : (a16 | (o16 << 16));
                if ((rr >> 1) == hiw)
                    *(unsigned*)&qs[(tile * 16 + lg * 4 + rr) * 40 + ct * 16 + (lr & ~1)] = pk;

                float ok = __shfl_xor(kc[rr], 1);
                a16 = f2b(kc[rr]); o16 = f2b(ok);
                pk = hiw ? (o16 | (a16 << 16)) : (a16 | (o16 << 16));
                if ((rr >> 1) == hiw)
                    *(unsigned*)&ks[(tile * 16 + lg * 4 + rr) * 40 + ct * 16 + (lr & ~1)] = pk;

                float ov = __shfl_xor(vc[rr], 1);
                a16 = f2b(vc[rr]); o16 = f2b(ov);
                pk = hiw ? (o16 | (a16 << 16)) : (a16 | (o16 << 16));
                if ((rr >> 1) == hiw)
                    *(unsigned*)&vs[(tile * 4 + lg) * 128 + ct * 64 + rr * 16 + (lr & ~1)] = pk;
            }
        }
    }
    __syncthreads();

    f32x4 c[6];
    {
        bf16x8 aq = *(const bf16x8*)&qs[(wave * 16 + lr) * 40 + lg * 8];
        #pragma unroll
        for (int j = 0; j < 6; j++) {
            bf16x8 bk = *(const bf16x8*)&ks[(j * 16 + lr) * 40 + lg * 8];
            f32x4 z = {0.f, 0.f, 0.f, 0.f};
            c[j] = __builtin_amdgcn_mfma_f32_16x16x32_bf16(aq, bk, z, 0, 0, 0);
        }
    }
    if (lr >= 10) { c[5][0] = -1e30f; c[5][1] = -1e30f; c[5][2] = -1e30f; c[5][3] = -1e30f; }

    #pragma unroll
    for (int rr = 0; rr < 4; rr++) {
        float m = c[0][rr];
        #pragma unroll
        for (int j = 1; j < 6; j++) m = fmaxf(m, c[j][rr]);
        m = fmaxf(m, __shfl_xor(m, 1));
        m = fmaxf(m, __shfl_xor(m, 2));
        m = fmaxf(m, __shfl_xor(m, 4));
        m = fmaxf(m, __shfl_xor(m, 8));
        float sum = 0.f;
        #pragma unroll
        for (int j = 0; j < 6; j++) {
            float e = __expf(c[j][rr] - m);
            c[j][rr] = e;
            sum += e;
        }
        sum += __shfl_xor(sum, 1);
        sum += __shfl_xor(sum, 2);
        sum += __shfl_xor(sum, 4);
        sum += __shfl_xor(sum, 8);
        float inv = 1.f / sum;
        #pragma unroll
        for (int j = 0; j < 6; j++) c[j][rr] *= inv;
    }
    __syncthreads();

    {
        int row_base = wave * 16 + lg * 4;
        #pragma unroll
        for (int j = 0; j < 6; j++) {
            #pragma unroll
            for (int rr = 0; rr < 4; rr++) {
                float oth = __shfl_xor(c[j][rr], 1);
                unsigned int own16 = f2b(c[j][rr]), oth16 = f2b(oth);
                unsigned int pk = hiw ? (oth16 | (own16 << 16)) : (own16 | (oth16 << 16));
                if ((rr >> 1) == hiw)
                    *(unsigned int*)&ps[(row_base + rr) * 104 + j * 16 + (lr & ~1)] = pk;
            }
        }
    }
    __syncthreads();

    {
        unsigned vbase = (unsigned)(size_t)&vs[0];
        f32x4 oc0 = {0.f,0.f,0.f,0.f}, oc1 = {0.f,0.f,0.f,0.f};
        #pragma unroll
        for (int s = 0; s < 3; s++) {
            bf16x8 ap = *(const bf16x8*)&ps[(wave * 16 + lr) * 104 + s * 32 + lg * 8];
            unsigned ta = vbase + (unsigned)((8 * s + 2 * lg) * 256) + (unsigned)(lr * 8);
            bf16x4 b0a, b0b, b1a, b1b;
            asm volatile(
                "ds_read_b64_tr_b16 %0, %4\n\t"
                "ds_read_b64_tr_b16 %1, %4 offset:256\n\t"
                "ds_read_b64_tr_b16 %2, %4 offset:128\n\t"
                "ds_read_b64_tr_b16 %3, %4 offset:384\n\t"
                "s_waitcnt lgkmcnt(0)"
                : "=&v"(b0a), "=&v"(b0b), "=&v"(b1a), "=&v"(b1b)
                : "v"(ta) : "memory");
            __builtin_amdgcn_sched_barrier(0);
            bf16x8 bv0, bv1;
            #pragma unroll
            for (int e = 0; e < 4; e++) {
                bv0[e] = b0a[e]; bv0[4 + e] = b0b[e];
                bv1[e] = b1a[e]; bv1[4 + e] = b1b[e];
            }
            oc0 = __builtin_amdgcn_mfma_f32_16x16x32_bf16(ap, bv0, oc0, 0, 0, 0);
            oc1 = __builtin_amdgcn_mfma_f32_16x16x32_bf16(ap, bv1, oc1, 0, 0, 0);
        }
        #pragma unroll
        for (int rr = 0; rr < 4; rr++) {
            int row = wave * 16 + lg * 4 + rr;
            if (row < 90) {
                size_t base = ((size_t)(n * 90 + row)) * 256 + h * 32;
                og[base + lr]      = f2b(oc0[rr]);
                og[base + 16 + lr] = f2b(oc1[rr]);
            }
        }
    }
}

// ---------------- swapped-orientation GEMM, 4 waves, 64r x 256c, 16 MFMA/wave/k-step ----------------
// C[M,NN] = A[M,K] @ Bt[NN,K]^T + bias, then RELU-store  -or-  LN(C+res)*g+b store.
// Wave wc owns rows ra0..ra0+63 x cols cb0+wc*64..+63.
// Thread (lr,lg): rows i*16+lr (i=0..3), cols wc*64+j*16+lg*4+{0..3} (j=0..3).
template<int RELU, int LN>
__global__ __launch_bounds__(256) void gemm3(
    const unsigned short* __restrict__ A, const unsigned short* __restrict__ Bt,
    const float* __restrict__ bias,
    const unsigned short* __restrict__ res, const float* __restrict__ g,
    const float* __restrict__ b,
    unsigned short* __restrict__ C, int M, int NN, int K)
{
    __shared__ __align__(16) unsigned short As[64 * 32];
    __shared__ __align__(16) unsigned short Bs[256 * 32];
    __shared__ float ssum[64 * 5], ssq[64 * 5];

    int bx = blockIdx.x;
    bx = (bx & 7) * 90 + (bx >> 3);           // XCD swizzle (grid.x == 720)
    int ra0 = bx * 64, cb0 = blockIdx.y * 256;

    int tid = threadIdx.x;
    int wave = tid >> 6, lane = tid & 63;
    int wc = wave;
    int lr = lane & 15, lg = lane >> 4;

    f32x4 acc[4][4];
    #pragma unroll
    for (int i = 0; i < 4; i++)
        #pragma unroll
        for (int j = 0; j < 4; j++)
            acc[i][j] = (f32x4){0.f, 0.f, 0.f, 0.f};

    for (int k0 = 0; k0 < K; k0 += 32) {
        __syncthreads();
        // 20 chunk-issues (16 B, 512 elems each): 16 for Bs, 4 for As; linear dest, pre-swizzled src
        for (int q = wave; q < 20; q += 4) {
            if (q < 16) {
                int c = q * 64 + lane;
                int r = c >> 2, sp = c & 3;
                int sl = sp ^ ((r >> 1) & 3);
                gll16(&Bt[(size_t)(cb0 + r) * K + k0 + sl * 8], &Bs[q * 512]);
            } else {
                int c = (q - 16) * 64 + lane;
                int r = c >> 2, sp = c & 3;
                int sl = sp ^ ((r >> 1) & 3);
                gll16(&A[(size_t)(ra0 + r) * K + k0 + sl * 8], &As[(q - 16) * 512]);
            }
        }
        __syncthreads();

        bf16x8 xw[4], ya[4];
        #pragma unroll
        for (int j = 0; j < 4; j++) {
            int nn = wc * 64 + j * 16 + lr;
            xw[j] = *(const bf16x8*)&Bs[nn * 32 + (lg ^ ((nn >> 1) & 3)) * 8];
        }
        #pragma unroll
        for (int i = 0; i < 4; i++) {
            int mm = i * 16 + lr;
            ya[i] = *(const bf16x8*)&As[mm * 32 + (lg ^ ((mm >> 1) & 3)) * 8];
        }
        #pragma unroll
        for (int i = 0; i < 4; i++)
            #pragma unroll
            for (int j = 0; j < 4; j++)
                acc[i][j] = __builtin_amdgcn_mfma_f32_16x16x32_bf16(xw[j], ya[i], acc[i][j], 0, 0, 0);
    }

    // epilogue
    float s[4] = {0.f,0.f,0.f,0.f}, s2[4] = {0.f,0.f,0.f,0.f};
    #pragma unroll
    for (int i = 0; i < 4; i++) {
        int row = ra0 + i * 16 + lr;
        #pragma unroll
        for (int j = 0; j < 4; j++) {
            int ncol = cb0 + wc * 64 + j * 16 + lg * 4;
            f32x4 bv = *(const f32x4*)&bias[ncol];
            #pragma unroll
            for (int rr = 0; rr < 4; rr++) acc[i][j][rr] += bv[rr];
            if (LN) {
                u16x4 rv = *(const u16x4*)&res[(size_t)row * 256 + ncol];
                #pragma unroll
                for (int rr = 0; rr < 4; rr++) {
                    acc[i][j][rr] += b2f(rv[rr]);
                    s[i] += acc[i][j][rr];
                    s2[i] += acc[i][j][rr] * acc[i][j][rr];
                }
            } else {
                u16x4 ov;
                #pragma unroll
                for (int rr = 0; rr < 4; rr++) {
                    float v = acc[i][j][rr];
                    if (RELU) v = fmaxf(v, 0.f);
                    ov[rr] = f2b(v);
                }
                *(u16x4*)&C[(size_t)row * NN + ncol] = ov;
            }
        }
    }

    if (LN) {
        #pragma unroll
        for (int i = 0; i < 4; i++) {
            s[i]  += __shfl_xor(s[i], 16);  s[i]  += __shfl_xor(s[i], 32);
            s2[i] += __shfl_xor(s2[i], 16); s2[i] += __shfl_xor(s2[i], 32);
            if (lg == 0) {
                int r64 = i * 16 + lr;
                ssum[r64 * 5 + wc] = s[i];
                ssq[r64 * 5 + wc]  = s2[i];
            }
        }
        __syncthreads();
        #pragma unroll
        for (int i = 0; i < 4; i++) {
            int r64 = i * 16 + lr;
            float ts = 0.f, tq = 0.f;
            #pragma unroll
            for (int w = 0; w < 4; w++) { ts += ssum[r64 * 5 + w]; tq += ssq[r64 * 5 + w]; }
            float mean = ts * (1.f / 256.f);
            float var = tq * (1.f / 256.f) - mean * mean;
            float inv = rsqrtf(var + 1e-5f);
            int row = ra0 + r64;
            #pragma unroll
            for (int j = 0; j < 4; j++) {
                int ncol = wc * 64 + j * 16 + lg * 4;
                f32x4 gv = *(const f32x4*)&g[ncol];
                f32x4 bv = *(const f32x4*)&b[ncol];
                u16x4 ov;
                #pragma unroll
                for (int rr = 0; rr < 4; rr++)
                    ov[rr] = f2b((acc[i][j][rr] - mean) * inv * gv[rr] + bv[rr]);
                *(u16x4*)&C[(size_t)row * 256 + ncol] = ov;
            }
        }
    }
}

// ---------------- classifier head ----------------
__global__ __launch_bounds__(256) void classifier(
    const unsigned short* __restrict__ xin,
    const float* __restrict__ Wc1, const float* __restrict__ bc1,
    const float* __restrict__ Wc2, const float* __restrict__ bc2,
    const float* __restrict__ Wc3, const float* __restrict__ bc3,
    float* __restrict__ out)
{
    __shared__ float w1[256][9];
    __shared__ float w2[64], b2s[8], w3[16], b3s[2], b1s[8];
    int t = threadIdx.x;
    #pragma unroll
    for (int i = 0; i < 8; i++) {
        int idx = t + i * 256;
        w1[idx >> 3][idx & 7] = Wc1[idx];
    }
    if (t < 64) w2[t] = Wc2[t];
    if (t < 16) w3[t] = Wc3[t];
    if (t < 8) { b2s[t] = bc2[t]; b1s[t] = bc1[t]; }
    if (t < 2) b3s[t] = bc3[t];
    __syncthreads();
    int g = t >> 3, m = t & 7;
    size_t row = (size_t)blockIdx.x * 32 + g;
    float z[8] = {0.f,0.f,0.f,0.f,0.f,0.f,0.f,0.f};
    const unsigned short* xr = xin + row * 256 + m * 32;
    #pragma unroll
    for (int cidx = 0; cidx < 4; cidx++) {
        u16x8 xv = *(const u16x8*)&xr[cidx * 8];
        #pragma unroll
        for (int e = 0; e < 8; e++) {
            float xf = b2f(xv[e]);
            int ei = m * 32 + cidx * 8 + e;
            #pragma unroll
            for (int j = 0; j < 8; j++) z[j] = fmaf(xf, w1[ei][j], z[j]);
        }
    }
    #pragma unroll
    for (int d = 1; d < 8; d <<= 1)
        #pragma unroll
        for (int j = 0; j < 8; j++) z[j] += __shfl_xor(z[j], d);
    float z1[8], z2[8];
    #pragma unroll
    for (int j = 0; j < 8; j++) z1[j] = tanhf(z[j] + b1s[j]);
    #pragma unroll
    for (int j2 = 0; j2 < 8; j2++) {
        float sacc = b2s[j2];
        #pragma unroll
        for (int j = 0; j < 8; j++) sacc = fmaf(z1[j], w2[j * 8 + j2], sacc);
        z2[j2] = tanhf(sacc);
    }
    if (m < 2) {
        float sacc = b3s[m];
        #pragma unroll
        for (int j = 0; j < 8; j++) sacc = fmaf(z2[j], w3[j * 2 + m], sacc);
        out[row * 2 + m] = 1.f / (1.f + __expf(-sacc));
    }
}

extern "C" void kernel_launch(void* const* d_in, const int* in_sizes, int n_in,
                              void* d_out, int out_size, void* d_ws, size_t ws_size,
                              hipStream_t stream) {
    const float* x        = (const float*)d_in[0];
    const float* q        = (const float*)d_in[1];
    const int*   positions= (const int*)d_in[2];
    const float* pos_emb  = (const float*)d_in[3];
    const float* Wq       = (const float*)d_in[4];
    const float* Wk       = (const float*)d_in[5];
    const float* Wv       = (const float*)d_in[6];
    const float* Wo       = (const float*)d_in[7];
    const float* bo       = (const float*)d_in[8];
    const float* g1       = (const float*)d_in[9];
    const float* b1       = (const float*)d_in[10];
    const float* g2       = (const float*)d_in[11];
    const float* b2       = (const float*)d_in[12];
    const float* Wf1      = (const float*)d_in[13];
    const float* bf1      = (const float*)d_in[14];
    const float* Wf2      = (const float*)d_in[15];
    const float* bf2      = (const float*)d_in[16];
    const float* Wc1      = (const float*)d_in[17];
    const float* bc1      = (const float*)d_in[18];
    const float* Wc2      = (const float*)d_in[19];
    const float* bc2      = (const float*)d_in[20];
    const float* Wc3      = (const float*)d_in[21];
    const float* bc3      = (const float*)d_in[22];
    float* out = (float*)d_out;

    const int R = 512 * 90;          // 46080 token rows
    char* ws = (char*)d_ws;
    size_t off = 0;
    auto alloc = [&](size_t bytes) -> void* {
        void* p = ws + off;
        off += (bytes + 255) & ~(size_t)255;
        return p;
    };
    unsigned short* cur = (unsigned short*)alloc((size_t)R * 256 * 2);
    unsigned short* qb  = (unsigned short*)alloc((size_t)R * 256 * 2);
    unsigned short* qho = (unsigned short*)alloc((size_t)R * 256 * 2);  // attn-out -> h (in-place LN)
    unsigned short* f1  = (unsigned short*)alloc((size_t)R * 1024 * 2);
    unsigned short* WoT = (unsigned short*)alloc((size_t)3 * 256 * 256 * 2);
    unsigned short* W1T = (unsigned short*)alloc((size_t)3 * 1024 * 256 * 2);
    unsigned short* W2T = (unsigned short*)alloc((size_t)3 * 256 * 1024 * 2);
    unsigned short* WTqkv = (unsigned short*)alloc((size_t)3 * 3 * 1024 * 2);

    for (int l = 0; l < 3; l++) {
        transpose_to_bf16<<<dim3(8, 8),  256, 0, stream>>>(Wo  + (size_t)l*256*256,  WoT + (size_t)l*256*256,  256, 256);
        transpose_to_bf16<<<dim3(8, 32), 256, 0, stream>>>(Wf1 + (size_t)l*256*1024, W1T + (size_t)l*1024*256, 256, 1024);
        transpose_to_bf16<<<dim3(32, 8), 256, 0, stream>>>(Wf2 + (size_t)l*1024*256, W2T + (size_t)l*256*1024, 1024, 256);
    }
    prep_wT<<<9, 256, 0, stream>>>(Wq, Wk, Wv, WTqkv);
    add_posemb<<<R, 256, 0, stream>>>(x, positions, pos_emb, cur);
    to_bf16_kernel<<<2048, 256, 0, stream>>>(q, qb, R * 256);

    for (int l = 0; l < 3; l++) {
        attn_kernel<<<512 * 8, 384, 0, stream>>>(cur, qb, WTqkv + (size_t)l * 3 * 1024, qho);
        // h = LN(attn_out @ Wo + bo + qb): in-place qho
        gemm3<0,1><<<dim3(720, 1), 256, 0, stream>>>(qho, WoT + (size_t)l*256*256, bo + l*256,
                                                     qb, g1 + l*256, b1 + l*256, qho, R, 256, 256);
        // f1 = relu(h @ Wf1 + bf1)
        gemm3<1,0><<<dim3(720, 4), 256, 0, stream>>>(qho, W1T + (size_t)l*1024*256, bf1 + l*1024,
                                                     nullptr, nullptr, nullptr, f1, R, 1024, 256);
        // cur = LN(f1 @ Wf2 + bf2 + h)
        gemm3<0,1><<<dim3(720, 1), 256, 0, stream>>>(f1, W2T + (size_t)l*256*1024, bf2 + l*256,
                                                     qho, g2 + l*256, b2 + l*256, cur, R, 256, 1024);
    }
    classifier<<<R / 32, 256, 0, stream>>>(cur, Wc1, bc1, Wc2, bc2, Wc3, bc3, out);
}

// Round 6
// 736.710 us; speedup vs baseline: 1.0281x; 1.0281x over previous
//
#include <hip/hip_runtime.h>

typedef __bf16 bf16x8 __attribute__((ext_vector_type(8)));
typedef __bf16 bf16x4 __attribute__((ext_vector_type(4)));
typedef float f32x4 __attribute__((ext_vector_type(4)));
typedef unsigned short u16x8 __attribute__((ext_vector_type(8)));
typedef unsigned short u16x4 __attribute__((ext_vector_type(4)));

__device__ __forceinline__ unsigned short f2b(float f) {
    union { float f; unsigned int u; } v; v.f = f;
    unsigned int r = v.u + 0x7fffu + ((v.u >> 16) & 1u);
    return (unsigned short)(r >> 16);
}
__device__ __forceinline__ float b2f(unsigned short b) {
    union { unsigned int u; float f; } v; v.u = ((unsigned int)b) << 16;
    return v.f;
}

__device__ __forceinline__ void gll16(const unsigned short* g, unsigned short* l) {
    __builtin_amdgcn_global_load_lds(
        (const __attribute__((address_space(1))) unsigned int*)g,
        (__attribute__((address_space(3))) unsigned int*)l, 16, 0, 0);
}

// ---------------- weight transpose + bf16 convert: W[K][NN] -> Wt[NN][K] ----------------
__global__ __launch_bounds__(256) void transpose_to_bf16(
    const float* __restrict__ W, unsigned short* __restrict__ Wt, int K, int NN)
{
    __shared__ float tile[32][33];
    int k0 = blockIdx.x * 32, n0 = blockIdx.y * 32;
    int tx = threadIdx.x & 31, ty = threadIdx.x >> 5;
    for (int r = ty; r < 32; r += 8)
        tile[r][tx] = W[(size_t)(k0 + r) * NN + n0 + tx];
    __syncthreads();
    for (int r = ty; r < 32; r += 8)
        Wt[(size_t)(n0 + r) * K + k0 + tx] = f2b(tile[tx][r]);
}

// ---------------- per-layer Q/K/V weight transpose ----------------
__global__ __launch_bounds__(256) void prep_wT(
    const float* __restrict__ Wq, const float* __restrict__ Wk, const float* __restrict__ Wv,
    unsigned short* __restrict__ wT)
{
    int l = blockIdx.x / 3, w = blockIdx.x % 3;
    const float* src = (w == 0 ? Wq : w == 1 ? Wk : Wv) + (size_t)l * 1024;
    unsigned short* dst = wT + ((size_t)l * 3 + w) * 1024;
    float scale = (w == 0) ? 0.0625f : 1.0f;
    int t = threadIdx.x;
    f32x4 v = *(const f32x4*)&src[t * 4];
    int d = (t * 4) >> 5, j0 = (t * 4) & 31;
    #pragma unroll
    for (int e = 0; e < 4; e++)
        dst[(j0 + e) * 32 + d] = f2b(v[e] * scale);
}

// ---------------- pe = x + pos_emb[positions] -> bf16 ----------------
__global__ __launch_bounds__(256) void add_posemb(
    const float* __restrict__ x, const int* __restrict__ pos,
    const float* __restrict__ pe, unsigned short* __restrict__ cur)
{
    size_t row = blockIdx.x;
    int t = threadIdx.x;
    int p = pos[row];
    float v = x[row * 256 + t] + pe[(size_t)p * 256 + t];
    cur[row * 256 + t] = f2b(v);
}

__global__ __launch_bounds__(256) void to_bf16_kernel(
    const float* __restrict__ in, unsigned short* __restrict__ o, int n)
{
    int i = blockIdx.x * 256 + threadIdx.x;
    int stride = gridDim.x * 256;
    for (; i < n; i += stride) o[i] = f2b(in[i]);
}

// ---------------- fused attention per (n,h): projections + softmax(QK^T)V ----------------
__global__ __launch_bounds__(384, 2) void attn_kernel(
    const unsigned short* __restrict__ cur, const unsigned short* __restrict__ qb,
    const unsigned short* __restrict__ wT,
    unsigned short* __restrict__ og)
{
    __shared__ __align__(16) unsigned short smem[96 * 104 + 96 * 32];
    unsigned short* qs = smem;             // [96][40]
    unsigned short* ks = smem + 96 * 40;   // [96][40]
    unsigned short* ps = smem;             // [96][104]
    unsigned short* vs = smem + 96 * 104;  // V subtiled

    int nh = blockIdx.x;
    int n = nh >> 3, h = nh & 7;
    int tid = threadIdx.x;
    int wave = tid >> 6, lane = tid & 63;
    int lr = lane & 15, lg = lane >> 4;
    int hiw = lane & 1;

    bf16x8 wq[2], wk[2], wv[2];
    #pragma unroll
    for (int ct = 0; ct < 2; ct++) {
        int o = (ct * 16 + lr) * 32 + lg * 8;
        wq[ct] = *(const bf16x8*)&wT[o];
        wk[ct] = *(const bf16x8*)&wT[1024 + o];
        wv[ct] = *(const bf16x8*)&wT[2048 + o];
    }

    {
        int tile = wave;
        int row = tile * 16 + lr;
        bf16x8 aq = {0,0,0,0,0,0,0,0}, ac = {0,0,0,0,0,0,0,0};
        if (row < 90) {
            size_t base = ((size_t)(n * 90 + row)) * 256 + h * 32 + lg * 8;
            aq = *(const bf16x8*)&qb[base];
            ac = *(const bf16x8*)&cur[base];
        }
        f32x4 zz = {0.f, 0.f, 0.f, 0.f};
        #pragma unroll
        for (int ct = 0; ct < 2; ct++) {
            f32x4 qc = __builtin_amdgcn_mfma_f32_16x16x32_bf16(aq, wq[ct], zz, 0, 0, 0);
            f32x4 kc = __builtin_amdgcn_mfma_f32_16x16x32_bf16(ac, wk[ct], zz, 0, 0, 0);
            f32x4 vc = __builtin_amdgcn_mfma_f32_16x16x32_bf16(ac, wv[ct], zz, 0, 0, 0);
            #pragma unroll
            for (int rr = 0; rr < 4; rr++) {
                float oq = __shfl_xor(qc[rr], 1);
                unsigned a16 = f2b(qc[rr]), o16 = f2b(oq);
                unsigned pk = hiw ? (o16 | (a16 << 16)) : (a16 | (o16 << 16));
                if ((rr >> 1) == hiw)
                    *(unsigned*)&qs[(tile * 16 + lg * 4 + rr) * 40 + ct * 16 + (lr & ~1)] = pk;

                float ok = __shfl_xor(kc[rr], 1);
                a16 = f2b(kc[rr]); o16 = f2b(ok);
                pk = hiw ? (o16 | (a16 << 16)) : (a16 | (o16 << 16));
                if ((rr >> 1) == hiw)
                    *(unsigned*)&ks[(tile * 16 + lg * 4 + rr) * 40 + ct * 16 + (lr & ~1)] = pk;

                float ov = __shfl_xor(vc[rr], 1);
                a16 = f2b(vc[rr]); o16 = f2b(ov);
                pk = hiw ? (o16 | (a16 << 16)) : (a16 | (o16 << 16));
                if ((rr >> 1) == hiw)
                    *(unsigned*)&vs[(tile * 4 + lg) * 128 + ct * 64 + rr * 16 + (lr & ~1)] = pk;
            }
        }
    }
    __syncthreads();

    f32x4 c[6];
    {
        bf16x8 aq = *(const bf16x8*)&qs[(wave * 16 + lr) * 40 + lg * 8];
        #pragma unroll
        for (int j = 0; j < 6; j++) {
            bf16x8 bk = *(const bf16x8*)&ks[(j * 16 + lr) * 40 + lg * 8];
            f32x4 z = {0.f, 0.f, 0.f, 0.f};
            c[j] = __builtin_amdgcn_mfma_f32_16x16x32_bf16(aq, bk, z, 0, 0, 0);
        }
    }
    if (lr >= 10) { c[5][0] = -1e30f; c[5][1] = -1e30f; c[5][2] = -1e30f; c[5][3] = -1e30f; }

    #pragma unroll
    for (int rr = 0; rr < 4; rr++) {
        float m = c[0][rr];
        #pragma unroll
        for (int j = 1; j < 6; j++) m = fmaxf(m, c[j][rr]);
        m = fmaxf(m, __shfl_xor(m, 1));
        m = fmaxf(m, __shfl_xor(m, 2));
        m = fmaxf(m, __shfl_xor(m, 4));
        m = fmaxf(m, __shfl_xor(m, 8));
        float sum = 0.f;
        #pragma unroll
        for (int j = 0; j < 6; j++) {
            float e = __expf(c[j][rr] - m);
            c[j][rr] = e;
            sum += e;
        }
        sum += __shfl_xor(sum, 1);
        sum += __shfl_xor(sum, 2);
        sum += __shfl_xor(sum, 4);
        sum += __shfl_xor(sum, 8);
        float inv = 1.f / sum;
        #pragma unroll
        for (int j = 0; j < 6; j++) c[j][rr] *= inv;
    }
    __syncthreads();

    {
        int row_base = wave * 16 + lg * 4;
        #pragma unroll
        for (int j = 0; j < 6; j++) {
            #pragma unroll
            for (int rr = 0; rr < 4; rr++) {
                float oth = __shfl_xor(c[j][rr], 1);
                unsigned int own16 = f2b(c[j][rr]), oth16 = f2b(oth);
                unsigned int pk = hiw ? (oth16 | (own16 << 16)) : (own16 | (oth16 << 16));
                if ((rr >> 1) == hiw)
                    *(unsigned int*)&ps[(row_base + rr) * 104 + j * 16 + (lr & ~1)] = pk;
            }
        }
    }
    __syncthreads();

    {
        unsigned vbase = (unsigned)(size_t)&vs[0];
        f32x4 oc0 = {0.f,0.f,0.f,0.f}, oc1 = {0.f,0.f,0.f,0.f};
        #pragma unroll
        for (int s = 0; s < 3; s++) {
            bf16x8 ap = *(const bf16x8*)&ps[(wave * 16 + lr) * 104 + s * 32 + lg * 8];
            unsigned ta = vbase + (unsigned)((8 * s + 2 * lg) * 256) + (unsigned)(lr * 8);
            bf16x4 b0a, b0b, b1a, b1b;
            asm volatile(
                "ds_read_b64_tr_b16 %0, %4\n\t"
                "ds_read_b64_tr_b16 %1, %4 offset:256\n\t"
                "ds_read_b64_tr_b16 %2, %4 offset:128\n\t"
                "ds_read_b64_tr_b16 %3, %4 offset:384\n\t"
                "s_waitcnt lgkmcnt(0)"
                : "=&v"(b0a), "=&v"(b0b), "=&v"(b1a), "=&v"(b1b)
                : "v"(ta) : "memory");
            __builtin_amdgcn_sched_barrier(0);
            bf16x8 bv0, bv1;
            #pragma unroll
            for (int e = 0; e < 4; e++) {
                bv0[e] = b0a[e]; bv0[4 + e] = b0b[e];
                bv1[e] = b1a[e]; bv1[4 + e] = b1b[e];
            }
            oc0 = __builtin_amdgcn_mfma_f32_16x16x32_bf16(ap, bv0, oc0, 0, 0, 0);
            oc1 = __builtin_amdgcn_mfma_f32_16x16x32_bf16(ap, bv1, oc1, 0, 0, 0);
        }
        #pragma unroll
        for (int rr = 0; rr < 4; rr++) {
            int row = wave * 16 + lg * 4 + rr;
            if (row < 90) {
                size_t base = ((size_t)(n * 90 + row)) * 256 + h * 32;
                og[base + lr]      = f2b(oc0[rr]);
                og[base + 16 + lr] = f2b(oc1[rr]);
            }
        }
    }
}

// ---------------- Wo GEMM + fused res/LN (4 waves, 64r x 256c) ----------------
template<int RELU, int LN>
__global__ __launch_bounds__(256) void gemm3(
    const unsigned short* __restrict__ A, const unsigned short* __restrict__ Bt,
    const float* __restrict__ bias,
    const unsigned short* __restrict__ res, const float* __restrict__ g,
    const float* __restrict__ b,
    unsigned short* __restrict__ C, int M, int NN, int K)
{
    __shared__ __align__(16) unsigned short As[64 * 32];
    __shared__ __align__(16) unsigned short Bs[256 * 32];
    __shared__ float ssum[64 * 5], ssq[64 * 5];

    int bx = blockIdx.x;
    bx = (bx & 7) * 90 + (bx >> 3);           // XCD swizzle (grid.x == 720)
    int ra0 = bx * 64, cb0 = blockIdx.y * 256;

    int tid = threadIdx.x;
    int wave = tid >> 6, lane = tid & 63;
    int wc = wave;
    int lr = lane & 15, lg = lane >> 4;

    f32x4 acc[4][4];
    #pragma unroll
    for (int i = 0; i < 4; i++)
        #pragma unroll
        for (int j = 0; j < 4; j++)
            acc[i][j] = (f32x4){0.f, 0.f, 0.f, 0.f};

    for (int k0 = 0; k0 < K; k0 += 32) {
        __syncthreads();
        for (int q = wave; q < 20; q += 4) {
            if (q < 16) {
                int c = q * 64 + lane;
                int r = c >> 2, sp = c & 3;
                int sl = sp ^ ((r >> 1) & 3);
                gll16(&Bt[(size_t)(cb0 + r) * K + k0 + sl * 8], &Bs[q * 512]);
            } else {
                int c = (q - 16) * 64 + lane;
                int r = c >> 2, sp = c & 3;
                int sl = sp ^ ((r >> 1) & 3);
                gll16(&A[(size_t)(ra0 + r) * K + k0 + sl * 8], &As[(q - 16) * 512]);
            }
        }
        __syncthreads();

        bf16x8 xw[4], ya[4];
        #pragma unroll
        for (int j = 0; j < 4; j++) {
            int nn = wc * 64 + j * 16 + lr;
            xw[j] = *(const bf16x8*)&Bs[nn * 32 + (lg ^ ((nn >> 1) & 3)) * 8];
        }
        #pragma unroll
        for (int i = 0; i < 4; i++) {
            int mm = i * 16 + lr;
            ya[i] = *(const bf16x8*)&As[mm * 32 + (lg ^ ((mm >> 1) & 3)) * 8];
        }
        #pragma unroll
        for (int i = 0; i < 4; i++)
            #pragma unroll
            for (int j = 0; j < 4; j++)
                acc[i][j] = __builtin_amdgcn_mfma_f32_16x16x32_bf16(xw[j], ya[i], acc[i][j], 0, 0, 0);
    }

    float s[4] = {0.f,0.f,0.f,0.f}, s2[4] = {0.f,0.f,0.f,0.f};
    #pragma unroll
    for (int i = 0; i < 4; i++) {
        int row = ra0 + i * 16 + lr;
        #pragma unroll
        for (int j = 0; j < 4; j++) {
            int ncol = cb0 + wc * 64 + j * 16 + lg * 4;
            f32x4 bv = *(const f32x4*)&bias[ncol];
            #pragma unroll
            for (int rr = 0; rr < 4; rr++) acc[i][j][rr] += bv[rr];
            if (LN) {
                u16x4 rv = *(const u16x4*)&res[(size_t)row * 256 + ncol];
                #pragma unroll
                for (int rr = 0; rr < 4; rr++) {
                    acc[i][j][rr] += b2f(rv[rr]);
                    s[i] += acc[i][j][rr];
                    s2[i] += acc[i][j][rr] * acc[i][j][rr];
                }
            } else {
                u16x4 ov;
                #pragma unroll
                for (int rr = 0; rr < 4; rr++) {
                    float v = acc[i][j][rr];
                    if (RELU) v = fmaxf(v, 0.f);
                    ov[rr] = f2b(v);
                }
                *(u16x4*)&C[(size_t)row * NN + ncol] = ov;
            }
        }
    }

    if (LN) {
        #pragma unroll
        for (int i = 0; i < 4; i++) {
            s[i]  += __shfl_xor(s[i], 16);  s[i]  += __shfl_xor(s[i], 32);
            s2[i] += __shfl_xor(s2[i], 16); s2[i] += __shfl_xor(s2[i], 32);
            if (lg == 0) {
                int r64 = i * 16 + lr;
                ssum[r64 * 5 + wc] = s[i];
                ssq[r64 * 5 + wc]  = s2[i];
            }
        }
        __syncthreads();
        #pragma unroll
        for (int i = 0; i < 4; i++) {
            int r64 = i * 16 + lr;
            float ts = 0.f, tq = 0.f;
            #pragma unroll
            for (int w = 0; w < 4; w++) { ts += ssum[r64 * 5 + w]; tq += ssq[r64 * 5 + w]; }
            float mean = ts * (1.f / 256.f);
            float var = tq * (1.f / 256.f) - mean * mean;
            float inv = rsqrtf(var + 1e-5f);
            int row = ra0 + r64;
            #pragma unroll
            for (int j = 0; j < 4; j++) {
                int ncol = wc * 64 + j * 16 + lg * 4;
                f32x4 gv = *(const f32x4*)&g[ncol];
                f32x4 bv = *(const f32x4*)&b[ncol];
                u16x4 ov;
                #pragma unroll
                for (int rr = 0; rr < 4; rr++)
                    ov[rr] = f2b((acc[i][j][rr] - mean) * inv * gv[rr] + bv[rr]);
                *(u16x4*)&C[(size_t)row * 256 + ncol] = ov;
            }
        }
    }
}

// ---------------- fused FFN: out = LN(relu(h@W1+bf1)@W2 + bf2 + h) ----------------
// Block = 64 token rows, 4 waves. 64 chained k-steps, 2-phase dbuf W staging.
// Order: FFN1(half0) 16 steps -> FFN2-partial(half0) 16 -> FFN1(half1) -> FFN2(half1) -> LN.
__device__ __forceinline__ void ffn_issue_stage(
    int s, unsigned short* dstbuf, int wave, int lane,
    const unsigned short* __restrict__ W1T, const unsigned short* __restrict__ W2T)
{
    int hf = s >> 5;
    int ph = (s >> 4) & 1;     // 0 = FFN1, 1 = FFN2
    #pragma unroll
    for (int ii = 0; ii < 4; ii++) {
        int q = wave * 4 + ii;                  // 0..15 (1KB each)
        int r = q * 16 + (lane >> 2);           // staged row 0..255
        int sp = lane & 3;
        int sl = sp ^ ((r >> 1) & 3);
        const unsigned short* src;
        if (ph == 0) {
            int sc = (s >> 3) & 1, kidx = s & 7;
            src = W1T + (size_t)(hf * 512 + sc * 256 + r) * 256 + kidx * 32 + sl * 8;
        } else {
            int kidx = s & 15;
            src = W2T + (size_t)r * 1024 + hf * 512 + kidx * 32 + sl * 8;
        }
        gll16(src, dstbuf + q * 512);
    }
}

__global__ __launch_bounds__(256) void ffn_fused(
    const unsigned short* __restrict__ h,
    const unsigned short* __restrict__ W1T, const float* __restrict__ bf1,
    const unsigned short* __restrict__ W2T, const float* __restrict__ bf2,
    const float* __restrict__ g2, const float* __restrict__ b2,
    unsigned short* __restrict__ outp)
{
    __shared__ __align__(16) unsigned short As[64 * 256];    // 32KB, chunk-swizzled p=c^(r&7)
    __shared__ __align__(16) unsigned short f1s[64 * 512];   // 64KB, chunk-swizzled p=c^(r&7)
    __shared__ __align__(16) unsigned short Ws[2 * 256 * 32];// 2x16KB dbuf, gemm3 swizzle
    __shared__ float b1ls[1024];
    __shared__ float ssum[64 * 5], ssq[64 * 5];

    int bx = blockIdx.x;
    bx = (bx & 7) * 90 + (bx >> 3);           // XCD swizzle (grid 720)
    int row0 = bx * 64;
    int tid = threadIdx.x;
    int wave = tid >> 6, lane = tid & 63;
    int lr = lane & 15, lg = lane >> 4;

    // ---- prologue: stage A (32KB), bf1 -> LDS, W step 0 ----
    for (int q = wave; q < 32; q += 4) {
        int r = q * 2 + (lane >> 5);
        int p = lane & 31;
        int sl = p ^ (r & 7);
        gll16(&h[(size_t)(row0 + r) * 256 + sl * 8], &As[q * 512]);
    }
    {
        f32x4 v = *(const f32x4*)&bf1[tid * 4];
        *(f32x4*)&b1ls[tid * 4] = v;
    }
    ffn_issue_stage(0, Ws, wave, lane, W1T, W2T);
    asm volatile("s_waitcnt vmcnt(0) lgkmcnt(0)" ::: "memory");
    __builtin_amdgcn_s_barrier();
    __builtin_amdgcn_sched_barrier(0);

    f32x4 acc2[4][4];
    #pragma unroll
    for (int i = 0; i < 4; i++)
        #pragma unroll
        for (int j = 0; j < 4; j++)
            acc2[i][j] = (f32x4){0.f, 0.f, 0.f, 0.f};

    int buf = 0;
    #pragma unroll 1
    for (int hf = 0; hf < 2; hf++) {
        // ---- FFN1: two 256-col subchunks, K=256 (8 steps each) ----
        #pragma unroll 1
        for (int sc = 0; sc < 2; sc++) {
            f32x4 acc1[4][4];
            #pragma unroll
            for (int i = 0; i < 4; i++)
                #pragma unroll
                for (int j = 0; j < 4; j++)
                    acc1[i][j] = (f32x4){0.f, 0.f, 0.f, 0.f};
            #pragma unroll 1
            for (int kidx = 0; kidx < 8; kidx++) {
                int s = hf * 32 + sc * 8 + kidx;
                ffn_issue_stage(s + 1, Ws + (buf ^ 1) * 8192, wave, lane, W1T, W2T);
                const unsigned short* wsb = Ws + buf * 8192;
                bf16x8 xw[4], ya[4];
                #pragma unroll
                for (int j = 0; j < 4; j++) {
                    int nn = wave * 64 + j * 16 + lr;
                    xw[j] = *(const bf16x8*)&wsb[nn * 32 + (lg ^ ((nn >> 1) & 3)) * 8];
                }
                #pragma unroll
                for (int i = 0; i < 4; i++) {
                    int mm = i * 16 + lr;
                    int c = kidx * 4 + lg;
                    ya[i] = *(const bf16x8*)&As[mm * 256 + (c ^ (mm & 7)) * 8];
                }
                #pragma unroll
                for (int i = 0; i < 4; i++)
                    #pragma unroll
                    for (int j = 0; j < 4; j++)
                        acc1[i][j] = __builtin_amdgcn_mfma_f32_16x16x32_bf16(xw[j], ya[i], acc1[i][j], 0, 0, 0);
                asm volatile("s_waitcnt vmcnt(0) lgkmcnt(0)" ::: "memory");
                __builtin_amdgcn_s_barrier();
                __builtin_amdgcn_sched_barrier(0);
                buf ^= 1;
            }
            // f1 epilogue: relu(acc1 + bf1) -> f1s (bf16, swizzled)
            #pragma unroll
            for (int i = 0; i < 4; i++) {
                int mm = i * 16 + lr;
                #pragma unroll
                for (int j = 0; j < 4; j++) {
                    int colh = sc * 256 + wave * 64 + j * 16 + lg * 4;   // 0..511
                    f32x4 bv = *(const f32x4*)&b1ls[hf * 512 + colh];
                    int c = colh >> 3;
                    int p = c ^ (mm & 7);
                    u16x4 ov;
                    #pragma unroll
                    for (int rr = 0; rr < 4; rr++)
                        ov[rr] = f2b(fmaxf(acc1[i][j][rr] + bv[rr], 0.f));
                    *(u16x4*)&f1s[mm * 512 + p * 8 + (colh & 7)] = ov;
                }
            }
        }
        // make f1s writes visible before FFN2 reads
        asm volatile("s_waitcnt lgkmcnt(0)" ::: "memory");
        __builtin_amdgcn_s_barrier();
        __builtin_amdgcn_sched_barrier(0);

        // ---- FFN2 partial: K = 512 (16 steps), accumulate into acc2 ----
        #pragma unroll 1
        for (int kidx = 0; kidx < 16; kidx++) {
            int s = hf * 32 + 16 + kidx;
            if (s + 1 < 64) ffn_issue_stage(s + 1, Ws + (buf ^ 1) * 8192, wave, lane, W1T, W2T);
            const unsigned short* wsb = Ws + buf * 8192;
            bf16x8 xw[4], ya[4];
            #pragma unroll
            for (int j = 0; j < 4; j++) {
                int nn = wave * 64 + j * 16 + lr;
                xw[j] = *(const bf16x8*)&wsb[nn * 32 + (lg ^ ((nn >> 1) & 3)) * 8];
            }
            #pragma unroll
            for (int i = 0; i < 4; i++) {
                int mm = i * 16 + lr;
                int c = kidx * 4 + lg;
                ya[i] = *(const bf16x8*)&f1s[mm * 512 + (c ^ (mm & 7)) * 8];
            }
            #pragma unroll
            for (int i = 0; i < 4; i++)
                #pragma unroll
                for (int j = 0; j < 4; j++)
                    acc2[i][j] = __builtin_amdgcn_mfma_f32_16x16x32_bf16(xw[j], ya[i], acc2[i][j], 0, 0, 0);
            if (s < 63) {
                asm volatile("s_waitcnt vmcnt(0) lgkmcnt(0)" ::: "memory");
                __builtin_amdgcn_s_barrier();
                __builtin_amdgcn_sched_barrier(0);
                buf ^= 1;
            }
        }
    }

    // ---- LN epilogue: out = LN(acc2 + bf2 + h)*g2 + b2 ----
    __syncthreads();
    float s1[4] = {0.f,0.f,0.f,0.f}, sq[4] = {0.f,0.f,0.f,0.f};
    #pragma unroll
    for (int i = 0; i < 4; i++) {
        int mm = i * 16 + lr;
        #pragma unroll
        for (int j = 0; j < 4; j++) {
            int col = wave * 64 + j * 16 + lg * 4;
            f32x4 bv = *(const f32x4*)&bf2[col];
            int c = col >> 3;
            u16x4 rv = *(const u16x4*)&As[mm * 256 + (c ^ (mm & 7)) * 8 + (col & 7)];
            #pragma unroll
            for (int rr = 0; rr < 4; rr++) {
                acc2[i][j][rr] += bv[rr] + b2f(rv[rr]);
                s1[i] += acc2[i][j][rr];
                sq[i] += acc2[i][j][rr] * acc2[i][j][rr];
            }
        }
    }
    #pragma unroll
    for (int i = 0; i < 4; i++) {
        s1[i] += __shfl_xor(s1[i], 16);  s1[i] += __shfl_xor(s1[i], 32);
        sq[i] += __shfl_xor(sq[i], 16);  sq[i] += __shfl_xor(sq[i], 32);
        if (lg == 0) {
            int r64 = i * 16 + lr;
            ssum[r64 * 5 + wave] = s1[i];
            ssq[r64 * 5 + wave]  = sq[i];
        }
    }
    __syncthreads();
    #pragma unroll
    for (int i = 0; i < 4; i++) {
        int r64 = i * 16 + lr;
        float ts = 0.f, tq = 0.f;
        #pragma unroll
        for (int w = 0; w < 4; w++) { ts += ssum[r64 * 5 + w]; tq += ssq[r64 * 5 + w]; }
        float mean = ts * (1.f / 256.f);
        float var = tq * (1.f / 256.f) - mean * mean;
        float inv = rsqrtf(var + 1e-5f);
        int row = row0 + r64;
        #pragma unroll
        for (int j = 0; j < 4; j++) {
            int col = wave * 64 + j * 16 + lg * 4;
            f32x4 gv = *(const f32x4*)&g2[col];
            f32x4 bv = *(const f32x4*)&b2[col];
            u16x4 ov;
            #pragma unroll
            for (int rr = 0; rr < 4; rr++)
                ov[rr] = f2b((acc2[i][j][rr] - mean) * inv * gv[rr] + bv[rr]);
            *(u16x4*)&outp[(size_t)row * 256 + col] = ov;
        }
    }
}

// ---------------- classifier head ----------------
__global__ __launch_bounds__(256) void classifier(
    const unsigned short* __restrict__ xin,
    const float* __restrict__ Wc1, const float* __restrict__ bc1,
    const float* __restrict__ Wc2, const float* __restrict__ bc2,
    const float* __restrict__ Wc3, const float* __restrict__ bc3,
    float* __restrict__ out)
{
    __shared__ float w1[256][9];
    __shared__ float w2[64], b2s[8], w3[16], b3s[2], b1s[8];
    int t = threadIdx.x;
    #pragma unroll
    for (int i = 0; i < 8; i++) {
        int idx = t + i * 256;
        w1[idx >> 3][idx & 7] = Wc1[idx];
    }
    if (t < 64) w2[t] = Wc2[t];
    if (t < 16) w3[t] = Wc3[t];
    if (t < 8) { b2s[t] = bc2[t]; b1s[t] = bc1[t]; }
    if (t < 2) b3s[t] = bc3[t];
    __syncthreads();
    int g = t >> 3, m = t & 7;
    size_t row = (size_t)blockIdx.x * 32 + g;
    float z[8] = {0.f,0.f,0.f,0.f,0.f,0.f,0.f,0.f};
    const unsigned short* xr = xin + row * 256 + m * 32;
    #pragma unroll
    for (int cidx = 0; cidx < 4; cidx++) {
        u16x8 xv = *(const u16x8*)&xr[cidx * 8];
        #pragma unroll
        for (int e = 0; e < 8; e++) {
            float xf = b2f(xv[e]);
            int ei = m * 32 + cidx * 8 + e;
            #pragma unroll
            for (int j = 0; j < 8; j++) z[j] = fmaf(xf, w1[ei][j], z[j]);
        }
    }
    #pragma unroll
    for (int d = 1; d < 8; d <<= 1)
        #pragma unroll
        for (int j = 0; j < 8; j++) z[j] += __shfl_xor(z[j], d);
    float z1[8], z2[8];
    #pragma unroll
    for (int j = 0; j < 8; j++) z1[j] = tanhf(z[j] + b1s[j]);
    #pragma unroll
    for (int j2 = 0; j2 < 8; j2++) {
        float sacc = b2s[j2];
        #pragma unroll
        for (int j = 0; j < 8; j++) sacc = fmaf(z1[j], w2[j * 8 + j2], sacc);
        z2[j2] = tanhf(sacc);
    }
    if (m < 2) {
        float sacc = b3s[m];
        #pragma unroll
        for (int j = 0; j < 8; j++) sacc = fmaf(z2[j], w3[j * 2 + m], sacc);
        out[row * 2 + m] = 1.f / (1.f + __expf(-sacc));
    }
}

extern "C" void kernel_launch(void* const* d_in, const int* in_sizes, int n_in,
                              void* d_out, int out_size, void* d_ws, size_t ws_size,
                              hipStream_t stream) {
    const float* x        = (const float*)d_in[0];
    const float* q        = (const float*)d_in[1];
    const int*   positions= (const int*)d_in[2];
    const float* pos_emb  = (const float*)d_in[3];
    const float* Wq       = (const float*)d_in[4];
    const float* Wk       = (const float*)d_in[5];
    const float* Wv       = (const float*)d_in[6];
    const float* Wo       = (const float*)d_in[7];
    const float* bo       = (const float*)d_in[8];
    const float* g1       = (const float*)d_in[9];
    const float* b1       = (const float*)d_in[10];
    const float* g2       = (const float*)d_in[11];
    const float* b2       = (const float*)d_in[12];
    const float* Wf1      = (const float*)d_in[13];
    const float* bf1      = (const float*)d_in[14];
    const float* Wf2      = (const float*)d_in[15];
    const float* bf2      = (const float*)d_in[16];
    const float* Wc1      = (const float*)d_in[17];
    const float* bc1      = (const float*)d_in[18];
    const float* Wc2      = (const float*)d_in[19];
    const float* bc2      = (const float*)d_in[20];
    const float* Wc3      = (const float*)d_in[21];
    const float* bc3      = (const float*)d_in[22];
    float* out = (float*)d_out;

    const int R = 512 * 90;          // 46080 token rows
    char* ws = (char*)d_ws;
    size_t off = 0;
    auto alloc = [&](size_t bytes) -> void* {
        void* p = ws + off;
        off += (bytes + 255) & ~(size_t)255;
        return p;
    };
    unsigned short* cur = (unsigned short*)alloc((size_t)R * 256 * 2);
    unsigned short* qb  = (unsigned short*)alloc((size_t)R * 256 * 2);
    unsigned short* qho = (unsigned short*)alloc((size_t)R * 256 * 2);  // attn-out -> h (in-place LN)
    unsigned short* WoT = (unsigned short*)alloc((size_t)3 * 256 * 256 * 2);
    unsigned short* W1T = (unsigned short*)alloc((size_t)3 * 1024 * 256 * 2);
    unsigned short* W2T = (unsigned short*)alloc((size_t)3 * 256 * 1024 * 2);
    unsigned short* WTqkv = (unsigned short*)alloc((size_t)3 * 3 * 1024 * 2);

    for (int l = 0; l < 3; l++) {
        transpose_to_bf16<<<dim3(8, 8),  256, 0, stream>>>(Wo  + (size_t)l*256*256,  WoT + (size_t)l*256*256,  256, 256);
        transpose_to_bf16<<<dim3(8, 32), 256, 0, stream>>>(Wf1 + (size_t)l*256*1024, W1T + (size_t)l*1024*256, 256, 1024);
        transpose_to_bf16<<<dim3(32, 8), 256, 0, stream>>>(Wf2 + (size_t)l*1024*256, W2T + (size_t)l*256*1024, 1024, 256);
    }
    prep_wT<<<9, 256, 0, stream>>>(Wq, Wk, Wv, WTqkv);
    add_posemb<<<R, 256, 0, stream>>>(x, positions, pos_emb, cur);
    to_bf16_kernel<<<2048, 256, 0, stream>>>(q, qb, R * 256);

    for (int l = 0; l < 3; l++) {
        attn_kernel<<<512 * 8, 384, 0, stream>>>(cur, qb, WTqkv + (size_t)l * 3 * 1024, qho);
        // h = LN(attn_out @ Wo + bo + qb): in-place qho
        gemm3<0,1><<<dim3(720, 1), 256, 0, stream>>>(qho, WoT + (size_t)l*256*256, bo + l*256,
                                                     qb, g1 + l*256, b1 + l*256, qho, R, 256, 256);
        // cur = LN(relu(h@W1+bf1)@W2 + bf2 + h)
        ffn_fused<<<720, 256, 0, stream>>>(qho,
                                           W1T + (size_t)l*1024*256, bf1 + l*1024,
                                           W2T + (size_t)l*256*1024, bf2 + l*256,
                                           g2 + l*256, b2 + l*256, cur);
    }
    classifier<<<R / 32, 256, 0, stream>>>(cur, Wc1, bc1, Wc2, bc2, Wc3, bc3, out);
}

// Round 7
// 662.666 us; speedup vs baseline: 1.1430x; 1.1117x over previous
//
#include <hip/hip_runtime.h>

typedef __bf16 bf16x8 __attribute__((ext_vector_type(8)));
typedef __bf16 bf16x4 __attribute__((ext_vector_type(4)));
typedef float f32x4 __attribute__((ext_vector_type(4)));
typedef unsigned short u16x8 __attribute__((ext_vector_type(8)));
typedef unsigned short u16x4 __attribute__((ext_vector_type(4)));

__device__ __forceinline__ unsigned short f2b(float f) {
    union { float f; unsigned int u; } v; v.f = f;
    unsigned int r = v.u + 0x7fffu + ((v.u >> 16) & 1u);
    return (unsigned short)(r >> 16);
}
__device__ __forceinline__ float b2f(unsigned short b) {
    union { unsigned int u; float f; } v; v.u = ((unsigned int)b) << 16;
    return v.f;
}

__device__ __forceinline__ void gll16(const unsigned short* g, unsigned short* l) {
    __builtin_amdgcn_global_load_lds(
        (const __attribute__((address_space(1))) unsigned int*)g,
        (__attribute__((address_space(3))) unsigned int*)l, 16, 0, 0);
}

// ---------------- weight transpose + bf16 convert: W[K][NN] -> Wt[NN][K] ----------------
__global__ __launch_bounds__(256) void transpose_to_bf16(
    const float* __restrict__ W, unsigned short* __restrict__ Wt, int K, int NN)
{
    __shared__ float tile[32][33];
    int k0 = blockIdx.x * 32, n0 = blockIdx.y * 32;
    int tx = threadIdx.x & 31, ty = threadIdx.x >> 5;
    for (int r = ty; r < 32; r += 8)
        tile[r][tx] = W[(size_t)(k0 + r) * NN + n0 + tx];
    __syncthreads();
    for (int r = ty; r < 32; r += 8)
        Wt[(size_t)(n0 + r) * K + k0 + tx] = f2b(tile[tx][r]);
}

// ---------------- per-layer Q/K/V weight transpose ----------------
__global__ __launch_bounds__(256) void prep_wT(
    const float* __restrict__ Wq, const float* __restrict__ Wk, const float* __restrict__ Wv,
    unsigned short* __restrict__ wT)
{
    int l = blockIdx.x / 3, w = blockIdx.x % 3;
    const float* src = (w == 0 ? Wq : w == 1 ? Wk : Wv) + (size_t)l * 1024;
    unsigned short* dst = wT + ((size_t)l * 3 + w) * 1024;
    float scale = (w == 0) ? 0.0625f : 1.0f;
    int t = threadIdx.x;
    f32x4 v = *(const f32x4*)&src[t * 4];
    int d = (t * 4) >> 5, j0 = (t * 4) & 31;
    #pragma unroll
    for (int e = 0; e < 4; e++)
        dst[(j0 + e) * 32 + d] = f2b(v[e] * scale);
}

// ---------------- pe = x + pos_emb[positions] -> bf16 ----------------
__global__ __launch_bounds__(256) void add_posemb(
    const float* __restrict__ x, const int* __restrict__ pos,
    const float* __restrict__ pe, unsigned short* __restrict__ cur)
{
    size_t row = blockIdx.x;
    int t = threadIdx.x;
    int p = pos[row];
    float v = x[row * 256 + t] + pe[(size_t)p * 256 + t];
    cur[row * 256 + t] = f2b(v);
}

__global__ __launch_bounds__(256) void to_bf16_kernel(
    const float* __restrict__ in, unsigned short* __restrict__ o, int n)
{
    int i = blockIdx.x * 256 + threadIdx.x;
    int stride = gridDim.x * 256;
    for (; i < n; i += stride) o[i] = f2b(in[i]);
}

// ---------------- fused attention per (n,h): projections + softmax(QK^T)V ----------------
__global__ __launch_bounds__(384, 2) void attn_kernel(
    const unsigned short* __restrict__ cur, const unsigned short* __restrict__ qb,
    const unsigned short* __restrict__ wT,
    unsigned short* __restrict__ og)
{
    __shared__ __align__(16) unsigned short smem[96 * 104 + 96 * 32];
    unsigned short* qs = smem;             // [96][40]
    unsigned short* ks = smem + 96 * 40;   // [96][40]
    unsigned short* ps = smem;             // [96][104]
    unsigned short* vs = smem + 96 * 104;  // V subtiled

    int nh = blockIdx.x;
    int n = nh >> 3, h = nh & 7;
    int tid = threadIdx.x;
    int wave = tid >> 6, lane = tid & 63;
    int lr = lane & 15, lg = lane >> 4;
    int hiw = lane & 1;

    bf16x8 wq[2], wk[2], wv[2];
    #pragma unroll
    for (int ct = 0; ct < 2; ct++) {
        int o = (ct * 16 + lr) * 32 + lg * 8;
        wq[ct] = *(const bf16x8*)&wT[o];
        wk[ct] = *(const bf16x8*)&wT[1024 + o];
        wv[ct] = *(const bf16x8*)&wT[2048 + o];
    }

    {
        int tile = wave;
        int row = tile * 16 + lr;
        bf16x8 aq = {0,0,0,0,0,0,0,0}, ac = {0,0,0,0,0,0,0,0};
        if (row < 90) {
            size_t base = ((size_t)(n * 90 + row)) * 256 + h * 32 + lg * 8;
            aq = *(const bf16x8*)&qb[base];
            ac = *(const bf16x8*)&cur[base];
        }
        f32x4 zz = {0.f, 0.f, 0.f, 0.f};
        #pragma unroll
        for (int ct = 0; ct < 2; ct++) {
            f32x4 qc = __builtin_amdgcn_mfma_f32_16x16x32_bf16(aq, wq[ct], zz, 0, 0, 0);
            f32x4 kc = __builtin_amdgcn_mfma_f32_16x16x32_bf16(ac, wk[ct], zz, 0, 0, 0);
            f32x4 vc = __builtin_amdgcn_mfma_f32_16x16x32_bf16(ac, wv[ct], zz, 0, 0, 0);
            #pragma unroll
            for (int rr = 0; rr < 4; rr++) {
                float oq = __shfl_xor(qc[rr], 1);
                unsigned a16 = f2b(qc[rr]), o16 = f2b(oq);
                unsigned pk = hiw ? (o16 | (a16 << 16)) : (a16 | (o16 << 16));
                if ((rr >> 1) == hiw)
                    *(unsigned*)&qs[(tile * 16 + lg * 4 + rr) * 40 + ct * 16 + (lr & ~1)] = pk;

                float ok = __shfl_xor(kc[rr], 1);
                a16 = f2b(kc[rr]); o16 = f2b(ok);
                pk = hiw ? (o16 | (a16 << 16)) : (a16 | (o16 << 16));
                if ((rr >> 1) == hiw)
                    *(unsigned*)&ks[(tile * 16 + lg * 4 + rr) * 40 + ct * 16 + (lr & ~1)] = pk;

                float ov = __shfl_xor(vc[rr], 1);
                a16 = f2b(vc[rr]); o16 = f2b(ov);
                pk = hiw ? (o16 | (a16 << 16)) : (a16 | (o16 << 16));
                if ((rr >> 1) == hiw)
                    *(unsigned*)&vs[(tile * 4 + lg) * 128 + ct * 64 + rr * 16 + (lr & ~1)] = pk;
            }
        }
    }
    __syncthreads();

    f32x4 c[6];
    {
        bf16x8 aq = *(const bf16x8*)&qs[(wave * 16 + lr) * 40 + lg * 8];
        #pragma unroll
        for (int j = 0; j < 6; j++) {
            bf16x8 bk = *(const bf16x8*)&ks[(j * 16 + lr) * 40 + lg * 8];
            f32x4 z = {0.f, 0.f, 0.f, 0.f};
            c[j] = __builtin_amdgcn_mfma_f32_16x16x32_bf16(aq, bk, z, 0, 0, 0);
        }
    }
    if (lr >= 10) { c[5][0] = -1e30f; c[5][1] = -1e30f; c[5][2] = -1e30f; c[5][3] = -1e30f; }

    #pragma unroll
    for (int rr = 0; rr < 4; rr++) {
        float m = c[0][rr];
        #pragma unroll
        for (int j = 1; j < 6; j++) m = fmaxf(m, c[j][rr]);
        m = fmaxf(m, __shfl_xor(m, 1));
        m = fmaxf(m, __shfl_xor(m, 2));
        m = fmaxf(m, __shfl_xor(m, 4));
        m = fmaxf(m, __shfl_xor(m, 8));
        float sum = 0.f;
        #pragma unroll
        for (int j = 0; j < 6; j++) {
            float e = __expf(c[j][rr] - m);
            c[j][rr] = e;
            sum += e;
        }
        sum += __shfl_xor(sum, 1);
        sum += __shfl_xor(sum, 2);
        sum += __shfl_xor(sum, 4);
        sum += __shfl_xor(sum, 8);
        float inv = 1.f / sum;
        #pragma unroll
        for (int j = 0; j < 6; j++) c[j][rr] *= inv;
    }
    __syncthreads();

    {
        int row_base = wave * 16 + lg * 4;
        #pragma unroll
        for (int j = 0; j < 6; j++) {
            #pragma unroll
            for (int rr = 0; rr < 4; rr++) {
                float oth = __shfl_xor(c[j][rr], 1);
                unsigned int own16 = f2b(c[j][rr]), oth16 = f2b(oth);
                unsigned int pk = hiw ? (oth16 | (own16 << 16)) : (own16 | (oth16 << 16));
                if ((rr >> 1) == hiw)
                    *(unsigned int*)&ps[(row_base + rr) * 104 + j * 16 + (lr & ~1)] = pk;
            }
        }
    }
    __syncthreads();

    {
        unsigned vbase = (unsigned)(size_t)&vs[0];
        f32x4 oc0 = {0.f,0.f,0.f,0.f}, oc1 = {0.f,0.f,0.f,0.f};
        #pragma unroll
        for (int s = 0; s < 3; s++) {
            bf16x8 ap = *(const bf16x8*)&ps[(wave * 16 + lr) * 104 + s * 32 + lg * 8];
            unsigned ta = vbase + (unsigned)((8 * s + 2 * lg) * 256) + (unsigned)(lr * 8);
            bf16x4 b0a, b0b, b1a, b1b;
            asm volatile(
                "ds_read_b64_tr_b16 %0, %4\n\t"
                "ds_read_b64_tr_b16 %1, %4 offset:256\n\t"
                "ds_read_b64_tr_b16 %2, %4 offset:128\n\t"
                "ds_read_b64_tr_b16 %3, %4 offset:384\n\t"
                "s_waitcnt lgkmcnt(0)"
                : "=&v"(b0a), "=&v"(b0b), "=&v"(b1a), "=&v"(b1b)
                : "v"(ta) : "memory");
            __builtin_amdgcn_sched_barrier(0);
            bf16x8 bv0, bv1;
            #pragma unroll
            for (int e = 0; e < 4; e++) {
                bv0[e] = b0a[e]; bv0[4 + e] = b0b[e];
                bv1[e] = b1a[e]; bv1[4 + e] = b1b[e];
            }
            oc0 = __builtin_amdgcn_mfma_f32_16x16x32_bf16(ap, bv0, oc0, 0, 0, 0);
            oc1 = __builtin_amdgcn_mfma_f32_16x16x32_bf16(ap, bv1, oc1, 0, 0, 0);
        }
        #pragma unroll
        for (int rr = 0; rr < 4; rr++) {
            int row = wave * 16 + lg * 4 + rr;
            if (row < 90) {
                size_t base = ((size_t)(n * 90 + row)) * 256 + h * 32;
                og[base + lr]      = f2b(oc0[rr]);
                og[base + 16 + lr] = f2b(oc1[rr]);
            }
        }
    }
}

// ---------------- templated swapped-orientation GEMM ----------------
// Block = (IM*16*WR) rows x (JN*16*WC) cols, 4 waves (WR x WC), 256 threads.
// C = A[M,K] @ Bt[NN,K]^T + bias, then RELU-store or LN(C+res)*g+b store.
// All LDS patterns use the round-5 measured-zero-conflict layout:
// rows of 32 bf16 (64 B), read swizzle lg ^ ((row>>1)&3), matching source pre-swizzle.
template<int IM, int JN, int WR, int WC, int RELU, int LN>
__global__ __launch_bounds__(256, 2) void gemm4(
    const unsigned short* __restrict__ A, const unsigned short* __restrict__ Bt,
    const float* __restrict__ bias,
    const unsigned short* __restrict__ res, const float* __restrict__ gw,
    const float* __restrict__ bw,
    unsigned short* __restrict__ C, int M, int NN, int K)
{
    constexpr int BM = IM * 16 * WR;
    constexpr int BN = JN * 16 * WC;
    constexpr int AG = BM / 16;       // A staging groups (512 elems each)
    constexpr int BG = BN / 16;       // B staging groups
    constexpr int SS = LN ? BM * WC : 1;
    __shared__ __align__(16) unsigned short As[BM * 32];
    __shared__ __align__(16) unsigned short Bs[BN * 32];
    __shared__ float ssum[SS], ssq[SS];

    int bx = blockIdx.x;
    int chunk = gridDim.x >> 3;               // grid.x divisible by 8
    bx = (bx & 7) * chunk + (bx >> 3);        // XCD swizzle
    int ra0 = bx * BM, cb0 = blockIdx.y * BN;

    int tid = threadIdx.x;
    int wave = tid >> 6, lane = tid & 63;
    int wr = wave / WC, wc = wave % WC;
    int lr = lane & 15, lg = lane >> 4;

    f32x4 acc[IM][JN];
    #pragma unroll
    for (int i = 0; i < IM; i++)
        #pragma unroll
        for (int j = 0; j < JN; j++)
            acc[i][j] = (f32x4){0.f, 0.f, 0.f, 0.f};

    for (int k0 = 0; k0 < K; k0 += 32) {
        __syncthreads();
        int rsub = lane >> 2, sp = lane & 3;
        for (int q = wave; q < AG + BG; q += 4) {
            if (q < BG) {
                int r = q * 16 + rsub;
                int sl = sp ^ ((r >> 1) & 3);
                gll16(&Bt[(size_t)(cb0 + r) * K + k0 + sl * 8], &Bs[q * 512]);
            } else {
                int r = (q - BG) * 16 + rsub;
                int sl = sp ^ ((r >> 1) & 3);
                gll16(&A[(size_t)(ra0 + r) * K + k0 + sl * 8], &As[(q - BG) * 512]);
            }
        }
        __syncthreads();

        bf16x8 xw[JN], ya[IM];
        #pragma unroll
        for (int j = 0; j < JN; j++) {
            int nn = wc * (JN * 16) + j * 16 + lr;
            xw[j] = *(const bf16x8*)&Bs[nn * 32 + (lg ^ ((nn >> 1) & 3)) * 8];
        }
        #pragma unroll
        for (int i = 0; i < IM; i++) {
            int mm = wr * (IM * 16) + i * 16 + lr;
            ya[i] = *(const bf16x8*)&As[mm * 32 + (lg ^ ((mm >> 1) & 3)) * 8];
        }
        #pragma unroll
        for (int i = 0; i < IM; i++)
            #pragma unroll
            for (int j = 0; j < JN; j++)
                acc[i][j] = __builtin_amdgcn_mfma_f32_16x16x32_bf16(xw[j], ya[i], acc[i][j], 0, 0, 0);
    }

    // epilogue: bias (+res, partial LN sums) then store
    float s1[IM], sq[IM];
    #pragma unroll
    for (int i = 0; i < IM; i++) { s1[i] = 0.f; sq[i] = 0.f; }

    #pragma unroll
    for (int i = 0; i < IM; i++) {
        int row = ra0 + wr * (IM * 16) + i * 16 + lr;
        #pragma unroll
        for (int j = 0; j < JN; j++) {
            int ncol = cb0 + wc * (JN * 16) + j * 16 + lg * 4;
            f32x4 bv = *(const f32x4*)&bias[ncol];
            #pragma unroll
            for (int rr = 0; rr < 4; rr++) acc[i][j][rr] += bv[rr];
            if (LN) {
                u16x4 rv = *(const u16x4*)&res[(size_t)row * NN + ncol];
                #pragma unroll
                for (int rr = 0; rr < 4; rr++) {
                    acc[i][j][rr] += b2f(rv[rr]);
                    s1[i] += acc[i][j][rr];
                    sq[i] += acc[i][j][rr] * acc[i][j][rr];
                }
            } else {
                u16x4 ov;
                #pragma unroll
                for (int rr = 0; rr < 4; rr++) {
                    float v = acc[i][j][rr];
                    if (RELU) v = fmaxf(v, 0.f);
                    ov[rr] = f2b(v);
                }
                *(u16x4*)&C[(size_t)row * NN + ncol] = ov;
            }
        }
    }

    if (LN) {
        #pragma unroll
        for (int i = 0; i < IM; i++) {
            s1[i] += __shfl_xor(s1[i], 16);  s1[i] += __shfl_xor(s1[i], 32);
            sq[i] += __shfl_xor(sq[i], 16);  sq[i] += __shfl_xor(sq[i], 32);
            if (lg == 0) {
                int rb = wr * (IM * 16) + i * 16 + lr;
                ssum[rb * WC + wc] = s1[i];
                ssq[rb * WC + wc]  = sq[i];
            }
        }
        __syncthreads();
        #pragma unroll
        for (int i = 0; i < IM; i++) {
            int rb = wr * (IM * 16) + i * 16 + lr;
            float ts = 0.f, tq = 0.f;
            #pragma unroll
            for (int w = 0; w < WC; w++) { ts += ssum[rb * WC + w]; tq += ssq[rb * WC + w]; }
            float mean = ts * (1.f / 256.f);
            float var = tq * (1.f / 256.f) - mean * mean;
            float inv = rsqrtf(var + 1e-5f);
            int row = ra0 + rb;
            #pragma unroll
            for (int j = 0; j < JN; j++) {
                int ncol = cb0 + wc * (JN * 16) + j * 16 + lg * 4;
                f32x4 gv = *(const f32x4*)&gw[ncol];
                f32x4 bv = *(const f32x4*)&bw[ncol];
                u16x4 ov;
                #pragma unroll
                for (int rr = 0; rr < 4; rr++)
                    ov[rr] = f2b((acc[i][j][rr] - mean) * inv * gv[rr] + bv[rr]);
                *(u16x4*)&C[(size_t)row * NN + ncol] = ov;
            }
        }
    }
}

// ---------------- classifier head ----------------
__global__ __launch_bounds__(256) void classifier(
    const unsigned short* __restrict__ xin,
    const float* __restrict__ Wc1, const float* __restrict__ bc1,
    const float* __restrict__ Wc2, const float* __restrict__ bc2,
    const float* __restrict__ Wc3, const float* __restrict__ bc3,
    float* __restrict__ out)
{
    __shared__ float w1[256][9];
    __shared__ float w2[64], b2s[8], w3[16], b3s[2], b1s[8];
    int t = threadIdx.x;
    #pragma unroll
    for (int i = 0; i < 8; i++) {
        int idx = t + i * 256;
        w1[idx >> 3][idx & 7] = Wc1[idx];
    }
    if (t < 64) w2[t] = Wc2[t];
    if (t < 16) w3[t] = Wc3[t];
    if (t < 8) { b2s[t] = bc2[t]; b1s[t] = bc1[t]; }
    if (t < 2) b3s[t] = bc3[t];
    __syncthreads();
    int g = t >> 3, m = t & 7;
    size_t row = (size_t)blockIdx.x * 32 + g;
    float z[8] = {0.f,0.f,0.f,0.f,0.f,0.f,0.f,0.f};
    const unsigned short* xr = xin + row * 256 + m * 32;
    #pragma unroll
    for (int cidx = 0; cidx < 4; cidx++) {
        u16x8 xv = *(const u16x8*)&xr[cidx * 8];
        #pragma unroll
        for (int e = 0; e < 8; e++) {
            float xf = b2f(xv[e]);
            int ei = m * 32 + cidx * 8 + e;
            #pragma unroll
            for (int j = 0; j < 8; j++) z[j] = fmaf(xf, w1[ei][j], z[j]);
        }
    }
    #pragma unroll
    for (int d = 1; d < 8; d <<= 1)
        #pragma unroll
        for (int j = 0; j < 8; j++) z[j] += __shfl_xor(z[j], d);
    float z1[8], z2[8];
    #pragma unroll
    for (int j = 0; j < 8; j++) z1[j] = tanhf(z[j] + b1s[j]);
    #pragma unroll
    for (int j2 = 0; j2 < 8; j2++) {
        float sacc = b2s[j2];
        #pragma unroll
        for (int j = 0; j < 8; j++) sacc = fmaf(z1[j], w2[j * 8 + j2], sacc);
        z2[j2] = tanhf(sacc);
    }
    if (m < 2) {
        float sacc = b3s[m];
        #pragma unroll
        for (int j = 0; j < 8; j++) sacc = fmaf(z2[j], w3[j * 2 + m], sacc);
        out[row * 2 + m] = 1.f / (1.f + __expf(-sacc));
    }
}

extern "C" void kernel_launch(void* const* d_in, const int* in_sizes, int n_in,
                              void* d_out, int out_size, void* d_ws, size_t ws_size,
                              hipStream_t stream) {
    const float* x        = (const float*)d_in[0];
    const float* q        = (const float*)d_in[1];
    const int*   positions= (const int*)d_in[2];
    const float* pos_emb  = (const float*)d_in[3];
    const float* Wq       = (const float*)d_in[4];
    const float* Wk       = (const float*)d_in[5];
    const float* Wv       = (const float*)d_in[6];
    const float* Wo       = (const float*)d_in[7];
    const float* bo       = (const float*)d_in[8];
    const float* g1       = (const float*)d_in[9];
    const float* b1       = (const float*)d_in[10];
    const float* g2       = (const float*)d_in[11];
    const float* b2       = (const float*)d_in[12];
    const float* Wf1      = (const float*)d_in[13];
    const float* bf1      = (const float*)d_in[14];
    const float* Wf2      = (const float*)d_in[15];
    const float* bf2      = (const float*)d_in[16];
    const float* Wc1      = (const float*)d_in[17];
    const float* bc1      = (const float*)d_in[18];
    const float* Wc2      = (const float*)d_in[19];
    const float* bc2      = (const float*)d_in[20];
    const float* Wc3      = (const float*)d_in[21];
    const float* bc3      = (const float*)d_in[22];
    float* out = (float*)d_out;

    const int R = 512 * 90;          // 46080 token rows
    char* ws = (char*)d_ws;
    size_t off = 0;
    auto alloc = [&](size_t bytes) -> void* {
        void* p = ws + off;
        off += (bytes + 255) & ~(size_t)255;
        return p;
    };
    unsigned short* cur = (unsigned short*)alloc((size_t)R * 256 * 2);
    unsigned short* qb  = (unsigned short*)alloc((size_t)R * 256 * 2);
    unsigned short* qho = (unsigned short*)alloc((size_t)R * 256 * 2);  // attn-out -> h (in-place LN)
    unsigned short* f1  = (unsigned short*)alloc((size_t)R * 1024 * 2);
    unsigned short* WoT = (unsigned short*)alloc((size_t)3 * 256 * 256 * 2);
    unsigned short* W1T = (unsigned short*)alloc((size_t)3 * 1024 * 256 * 2);
    unsigned short* W2T = (unsigned short*)alloc((size_t)3 * 256 * 1024 * 2);
    unsigned short* WTqkv = (unsigned short*)alloc((size_t)3 * 3 * 1024 * 2);

    for (int l = 0; l < 3; l++) {
        transpose_to_bf16<<<dim3(8, 8),  256, 0, stream>>>(Wo  + (size_t)l*256*256,  WoT + (size_t)l*256*256,  256, 256);
        transpose_to_bf16<<<dim3(8, 32), 256, 0, stream>>>(Wf1 + (size_t)l*256*1024, W1T + (size_t)l*1024*256, 256, 1024);
        transpose_to_bf16<<<dim3(32, 8), 256, 0, stream>>>(Wf2 + (size_t)l*1024*256, W2T + (size_t)l*256*1024, 1024, 256);
    }
    prep_wT<<<9, 256, 0, stream>>>(Wq, Wk, Wv, WTqkv);
    add_posemb<<<R, 256, 0, stream>>>(x, positions, pos_emb, cur);
    to_bf16_kernel<<<2048, 256, 0, stream>>>(q, qb, R * 256);

    for (int l = 0; l < 3; l++) {
        attn_kernel<<<512 * 8, 384, 0, stream>>>(cur, qb, WTqkv + (size_t)l * 3 * 1024, qho);
        // h = LN(attn_out @ Wo + bo + qb): in-place qho   (96x256 tile, 480 blocks)
        gemm4<6,4,1,4,0,1><<<dim3(480, 1), 256, 0, stream>>>(
            qho, WoT + (size_t)l*256*256, bo + l*256,
            qb, g1 + l*256, b1 + l*256, qho, R, 256, 256);
        // f1 = relu(h @ Wf1 + bf1)   (128x256 tile, 360x4 blocks)
        gemm4<4,8,2,2,1,0><<<dim3(360, 4), 256, 0, stream>>>(
            qho, W1T + (size_t)l*1024*256, bf1 + l*1024,
            nullptr, nullptr, nullptr, f1, R, 1024, 256);
        // cur = LN(f1 @ Wf2 + bf2 + h)   (96x256 tile, 480 blocks)
        gemm4<6,4,1,4,0,1><<<dim3(480, 1), 256, 0, stream>>>(
            f1, W2T + (size_t)l*256*1024, bf2 + l*256,
            qho, g2 + l*256, b2 + l*256, cur, R, 256, 1024);
    }
    classifier<<<R / 32, 256, 0, stream>>>(cur, Wc1, bc1, Wc2, bc2, Wc3, bc3, out);
}

// Round 8
// 628.174 us; speedup vs baseline: 1.2058x; 1.0549x over previous
//
#include <hip/hip_runtime.h>

typedef __bf16 bf16x8 __attribute__((ext_vector_type(8)));
typedef __bf16 bf16x4 __attribute__((ext_vector_type(4)));
typedef float f32x4 __attribute__((ext_vector_type(4)));
typedef unsigned short u16x8 __attribute__((ext_vector_type(8)));
typedef unsigned short u16x4 __attribute__((ext_vector_type(4)));

__device__ __forceinline__ unsigned short f2b(float f) {
    union { float f; unsigned int u; } v; v.f = f;
    unsigned int r = v.u + 0x7fffu + ((v.u >> 16) & 1u);
    return (unsigned short)(r >> 16);
}
__device__ __forceinline__ float b2f(unsigned short b) {
    union { unsigned int u; float f; } v; v.u = ((unsigned int)b) << 16;
    return v.f;
}

__device__ __forceinline__ void gll16(const unsigned short* g, unsigned short* l) {
    __builtin_amdgcn_global_load_lds(
        (const __attribute__((address_space(1))) unsigned int*)g,
        (__attribute__((address_space(3))) unsigned int*)l, 16, 0, 0);
}

// ---------------- weight transpose + bf16 convert: W[K][NN] -> Wt[NN][K] ----------------
__global__ __launch_bounds__(256) void transpose_to_bf16(
    const float* __restrict__ W, unsigned short* __restrict__ Wt, int K, int NN)
{
    __shared__ float tile[32][33];
    int k0 = blockIdx.x * 32, n0 = blockIdx.y * 32;
    int tx = threadIdx.x & 31, ty = threadIdx.x >> 5;
    for (int r = ty; r < 32; r += 8)
        tile[r][tx] = W[(size_t)(k0 + r) * NN + n0 + tx];
    __syncthreads();
    for (int r = ty; r < 32; r += 8)
        Wt[(size_t)(n0 + r) * K + k0 + tx] = f2b(tile[tx][r]);
}

// ---------------- per-layer Q/K/V weight transpose ----------------
__global__ __launch_bounds__(256) void prep_wT(
    const float* __restrict__ Wq, const float* __restrict__ Wk, const float* __restrict__ Wv,
    unsigned short* __restrict__ wT)
{
    int l = blockIdx.x / 3, w = blockIdx.x % 3;
    const float* src = (w == 0 ? Wq : w == 1 ? Wk : Wv) + (size_t)l * 1024;
    unsigned short* dst = wT + ((size_t)l * 3 + w) * 1024;
    float scale = (w == 0) ? 0.0625f : 1.0f;
    int t = threadIdx.x;
    f32x4 v = *(const f32x4*)&src[t * 4];
    int d = (t * 4) >> 5, j0 = (t * 4) & 31;
    #pragma unroll
    for (int e = 0; e < 4; e++)
        dst[(j0 + e) * 32 + d] = f2b(v[e] * scale);
}

// ---------------- pe = x + pos_emb[positions] -> bf16 ----------------
__global__ __launch_bounds__(256) void add_posemb(
    const float* __restrict__ x, const int* __restrict__ pos,
    const float* __restrict__ pe, unsigned short* __restrict__ cur)
{
    size_t row = blockIdx.x;
    int t = threadIdx.x;
    int p = pos[row];
    float v = x[row * 256 + t] + pe[(size_t)p * 256 + t];
    cur[row * 256 + t] = f2b(v);
}

__global__ __launch_bounds__(256) void to_bf16_kernel(
    const float* __restrict__ in, unsigned short* __restrict__ o, int n)
{
    int i = blockIdx.x * 256 + threadIdx.x;
    int stride = gridDim.x * 256;
    for (; i < n; i += stride) o[i] = f2b(in[i]);
}

// ---------------- fused attention per (n,h): projections + softmax(QK^T)V ----------------
__global__ __launch_bounds__(384, 2) void attn_kernel(
    const unsigned short* __restrict__ cur, const unsigned short* __restrict__ qb,
    const unsigned short* __restrict__ wT,
    unsigned short* __restrict__ og)
{
    __shared__ __align__(16) unsigned short smem[96 * 104 + 96 * 32];
    unsigned short* qs = smem;             // [96][40]
    unsigned short* ks = smem + 96 * 40;   // [96][40]
    unsigned short* ps = smem;             // [96][104]
    unsigned short* vs = smem + 96 * 104;  // V subtiled

    int nh = blockIdx.x;
    int n = nh >> 3, h = nh & 7;
    int tid = threadIdx.x;
    int wave = tid >> 6, lane = tid & 63;
    int lr = lane & 15, lg = lane >> 4;
    int hiw = lane & 1;

    bf16x8 wq[2], wk[2], wv[2];
    #pragma unroll
    for (int ct = 0; ct < 2; ct++) {
        int o = (ct * 16 + lr) * 32 + lg * 8;
        wq[ct] = *(const bf16x8*)&wT[o];
        wk[ct] = *(const bf16x8*)&wT[1024 + o];
        wv[ct] = *(const bf16x8*)&wT[2048 + o];
    }

    {
        int tile = wave;
        int row = tile * 16 + lr;
        bf16x8 aq = {0,0,0,0,0,0,0,0}, ac = {0,0,0,0,0,0,0,0};
        if (row < 90) {
            size_t base = ((size_t)(n * 90 + row)) * 256 + h * 32 + lg * 8;
            aq = *(const bf16x8*)&qb[base];
            ac = *(const bf16x8*)&cur[base];
        }
        f32x4 zz = {0.f, 0.f, 0.f, 0.f};
        #pragma unroll
        for (int ct = 0; ct < 2; ct++) {
            f32x4 qc = __builtin_amdgcn_mfma_f32_16x16x32_bf16(aq, wq[ct], zz, 0, 0, 0);
            f32x4 kc = __builtin_amdgcn_mfma_f32_16x16x32_bf16(ac, wk[ct], zz, 0, 0, 0);
            f32x4 vc = __builtin_amdgcn_mfma_f32_16x16x32_bf16(ac, wv[ct], zz, 0, 0, 0);
            #pragma unroll
            for (int rr = 0; rr < 4; rr++) {
                float oq = __shfl_xor(qc[rr], 1);
                unsigned a16 = f2b(qc[rr]), o16 = f2b(oq);
                unsigned pk = hiw ? (o16 | (a16 << 16)) : (a16 | (o16 << 16));
                if ((rr >> 1) == hiw)
                    *(unsigned*)&qs[(tile * 16 + lg * 4 + rr) * 40 + ct * 16 + (lr & ~1)] = pk;

                float ok = __shfl_xor(kc[rr], 1);
                a16 = f2b(kc[rr]); o16 = f2b(ok);
                pk = hiw ? (o16 | (a16 << 16)) : (a16 | (o16 << 16));
                if ((rr >> 1) == hiw)
                    *(unsigned*)&ks[(tile * 16 + lg * 4 + rr) * 40 + ct * 16 + (lr & ~1)] = pk;

                float ov = __shfl_xor(vc[rr], 1);
                a16 = f2b(vc[rr]); o16 = f2b(ov);
                pk = hiw ? (o16 | (a16 << 16)) : (a16 | (o16 << 16));
                if ((rr >> 1) == hiw)
                    *(unsigned*)&vs[(tile * 4 + lg) * 128 + ct * 64 + rr * 16 + (lr & ~1)] = pk;
            }
        }
    }
    __syncthreads();

    f32x4 c[6];
    {
        bf16x8 aq = *(const bf16x8*)&qs[(wave * 16 + lr) * 40 + lg * 8];
        #pragma unroll
        for (int j = 0; j < 6; j++) {
            bf16x8 bk = *(const bf16x8*)&ks[(j * 16 + lr) * 40 + lg * 8];
            f32x4 z = {0.f, 0.f, 0.f, 0.f};
            c[j] = __builtin_amdgcn_mfma_f32_16x16x32_bf16(aq, bk, z, 0, 0, 0);
        }
    }
    if (lr >= 10) { c[5][0] = -1e30f; c[5][1] = -1e30f; c[5][2] = -1e30f; c[5][3] = -1e30f; }

    #pragma unroll
    for (int rr = 0; rr < 4; rr++) {
        float m = c[0][rr];
        #pragma unroll
        for (int j = 1; j < 6; j++) m = fmaxf(m, c[j][rr]);
        m = fmaxf(m, __shfl_xor(m, 1));
        m = fmaxf(m, __shfl_xor(m, 2));
        m = fmaxf(m, __shfl_xor(m, 4));
        m = fmaxf(m, __shfl_xor(m, 8));
        float sum = 0.f;
        #pragma unroll
        for (int j = 0; j < 6; j++) {
            float e = __expf(c[j][rr] - m);
            c[j][rr] = e;
            sum += e;
        }
        sum += __shfl_xor(sum, 1);
        sum += __shfl_xor(sum, 2);
        sum += __shfl_xor(sum, 4);
        sum += __shfl_xor(sum, 8);
        float inv = 1.f / sum;
        #pragma unroll
        for (int j = 0; j < 6; j++) c[j][rr] *= inv;
    }
    __syncthreads();

    {
        int row_base = wave * 16 + lg * 4;
        #pragma unroll
        for (int j = 0; j < 6; j++) {
            #pragma unroll
            for (int rr = 0; rr < 4; rr++) {
                float oth = __shfl_xor(c[j][rr], 1);
                unsigned int own16 = f2b(c[j][rr]), oth16 = f2b(oth);
                unsigned int pk = hiw ? (oth16 | (own16 << 16)) : (own16 | (oth16 << 16));
                if ((rr >> 1) == hiw)
                    *(unsigned int*)&ps[(row_base + rr) * 104 + j * 16 + (lr & ~1)] = pk;
            }
        }
    }
    __syncthreads();

    {
        unsigned vbase = (unsigned)(size_t)&vs[0];
        f32x4 oc0 = {0.f,0.f,0.f,0.f}, oc1 = {0.f,0.f,0.f,0.f};
        #pragma unroll
        for (int s = 0; s < 3; s++) {
            bf16x8 ap = *(const bf16x8*)&ps[(wave * 16 + lr) * 104 + s * 32 + lg * 8];
            unsigned ta = vbase + (unsigned)((8 * s + 2 * lg) * 256) + (unsigned)(lr * 8);
            bf16x4 b0a, b0b, b1a, b1b;
            asm volatile(
                "ds_read_b64_tr_b16 %0, %4\n\t"
                "ds_read_b64_tr_b16 %1, %4 offset:256\n\t"
                "ds_read_b64_tr_b16 %2, %4 offset:128\n\t"
                "ds_read_b64_tr_b16 %3, %4 offset:384\n\t"
                "s_waitcnt lgkmcnt(0)"
                : "=&v"(b0a), "=&v"(b0b), "=&v"(b1a), "=&v"(b1b)
                : "v"(ta) : "memory");
            __builtin_amdgcn_sched_barrier(0);
            bf16x8 bv0, bv1;
            #pragma unroll
            for (int e = 0; e < 4; e++) {
                bv0[e] = b0a[e]; bv0[4 + e] = b0b[e];
                bv1[e] = b1a[e]; bv1[4 + e] = b1b[e];
            }
            oc0 = __builtin_amdgcn_mfma_f32_16x16x32_bf16(ap, bv0, oc0, 0, 0, 0);
            oc1 = __builtin_amdgcn_mfma_f32_16x16x32_bf16(ap, bv1, oc1, 0, 0, 0);
        }
        #pragma unroll
        for (int rr = 0; rr < 4; rr++) {
            int row = wave * 16 + lg * 4 + rr;
            if (row < 90) {
                size_t base = ((size_t)(n * 90 + row)) * 256 + h * 32;
                og[base + lr]      = f2b(oc0[rr]);
                og[base + 16 + lr] = f2b(oc1[rr]);
            }
        }
    }
}

// ---------------- 2-phase double-buffered swapped-orientation GEMM ----------------
// Block = (IM*16*WR) rows x (JN*16*WC) cols, 4 waves (WR x WC), 256 threads.
// k-loop: stage(t+1 -> buf^1) issued BEFORE compute(buf); ONE vmcnt(0)+barrier per step.
template<int IM, int JN, int WR, int WC, int RELU, int LN>
__global__ __launch_bounds__(256, 2) void gemm5(
    const unsigned short* __restrict__ A, const unsigned short* __restrict__ Bt,
    const float* __restrict__ bias,
    const unsigned short* __restrict__ res, const float* __restrict__ gw,
    const float* __restrict__ bw,
    unsigned short* __restrict__ C, int M, int NN, int K)
{
    constexpr int BM = IM * 16 * WR;
    constexpr int BN = JN * 16 * WC;
    constexpr int AG = BM / 16;       // A staging groups (512 elems each)
    constexpr int BG = BN / 16;       // B staging groups
    constexpr int SS = LN ? BM * WC : 1;
    __shared__ __align__(16) unsigned short As[2][BM * 32];
    __shared__ __align__(16) unsigned short Bs[2][BN * 32];
    __shared__ float ssum[SS], ssq[SS];

    int bx = blockIdx.x;
    int chunk = gridDim.x >> 3;               // grid.x divisible by 8
    bx = (bx & 7) * chunk + (bx >> 3);        // XCD swizzle
    int ra0 = bx * BM, cb0 = blockIdx.y * BN;

    int tid = threadIdx.x;
    int wave = tid >> 6, lane = tid & 63;
    int wr = wave / WC, wc = wave % WC;
    int lr = lane & 15, lg = lane >> 4;
    int rsub = lane >> 2, sp = lane & 3;

    auto stage = [&](int k0, int bsel) {
        for (int q = wave; q < AG + BG; q += 4) {
            if (q < BG) {
                int r = q * 16 + rsub;
                int sl = sp ^ ((r >> 1) & 3);
                gll16(&Bt[(size_t)(cb0 + r) * K + k0 + sl * 8], &Bs[bsel][q * 512]);
            } else {
                int r = (q - BG) * 16 + rsub;
                int sl = sp ^ ((r >> 1) & 3);
                gll16(&A[(size_t)(ra0 + r) * K + k0 + sl * 8], &As[bsel][(q - BG) * 512]);
            }
        }
    };

    f32x4 acc[IM][JN];
    #pragma unroll
    for (int i = 0; i < IM; i++)
        #pragma unroll
        for (int j = 0; j < JN; j++)
            acc[i][j] = (f32x4){0.f, 0.f, 0.f, 0.f};

    // prologue
    stage(0, 0);
    asm volatile("s_waitcnt vmcnt(0)" ::: "memory");
    __builtin_amdgcn_s_barrier();
    __builtin_amdgcn_sched_barrier(0);

    int cur = 0;
    for (int k0 = 0; k0 < K; k0 += 32) {
        if (k0 + 32 < K) stage(k0 + 32, cur ^ 1);
        __builtin_amdgcn_sched_barrier(0);    // keep stage issue ahead of compute

        bf16x8 xw[JN], ya[IM];
        #pragma unroll
        for (int j = 0; j < JN; j++) {
            int nn = wc * (JN * 16) + j * 16 + lr;
            xw[j] = *(const bf16x8*)&Bs[cur][nn * 32 + (lg ^ ((nn >> 1) & 3)) * 8];
        }
        #pragma unroll
        for (int i = 0; i < IM; i++) {
            int mm = wr * (IM * 16) + i * 16 + lr;
            ya[i] = *(const bf16x8*)&As[cur][mm * 32 + (lg ^ ((mm >> 1) & 3)) * 8];
        }
        #pragma unroll
        for (int i = 0; i < IM; i++)
            #pragma unroll
            for (int j = 0; j < JN; j++)
                acc[i][j] = __builtin_amdgcn_mfma_f32_16x16x32_bf16(xw[j], ya[i], acc[i][j], 0, 0, 0);

        asm volatile("s_waitcnt vmcnt(0)" ::: "memory");
        __builtin_amdgcn_s_barrier();
        __builtin_amdgcn_sched_barrier(0);
        cur ^= 1;
    }

    // epilogue: bias (+res, partial LN sums) then store
    float s1[IM], sq[IM];
    #pragma unroll
    for (int i = 0; i < IM; i++) { s1[i] = 0.f; sq[i] = 0.f; }

    #pragma unroll
    for (int i = 0; i < IM; i++) {
        int row = ra0 + wr * (IM * 16) + i * 16 + lr;
        #pragma unroll
        for (int j = 0; j < JN; j++) {
            int ncol = cb0 + wc * (JN * 16) + j * 16 + lg * 4;
            f32x4 bv = *(const f32x4*)&bias[ncol];
            #pragma unroll
            for (int rr = 0; rr < 4; rr++) acc[i][j][rr] += bv[rr];
            if (LN) {
                u16x4 rv = *(const u16x4*)&res[(size_t)row * NN + ncol];
                #pragma unroll
                for (int rr = 0; rr < 4; rr++) {
                    acc[i][j][rr] += b2f(rv[rr]);
                    s1[i] += acc[i][j][rr];
                    sq[i] += acc[i][j][rr] * acc[i][j][rr];
                }
            } else {
                u16x4 ov;
                #pragma unroll
                for (int rr = 0; rr < 4; rr++) {
                    float v = acc[i][j][rr];
                    if (RELU) v = fmaxf(v, 0.f);
                    ov[rr] = f2b(v);
                }
                *(u16x4*)&C[(size_t)row * NN + ncol] = ov;
            }
        }
    }

    if (LN) {
        #pragma unroll
        for (int i = 0; i < IM; i++) {
            s1[i] += __shfl_xor(s1[i], 16);  s1[i] += __shfl_xor(s1[i], 32);
            sq[i] += __shfl_xor(sq[i], 16);  sq[i] += __shfl_xor(sq[i], 32);
            if (lg == 0) {
                int rb = wr * (IM * 16) + i * 16 + lr;
                ssum[rb * WC + wc] = s1[i];
                ssq[rb * WC + wc]  = sq[i];
            }
        }
        __syncthreads();
        #pragma unroll
        for (int i = 0; i < IM; i++) {
            int rb = wr * (IM * 16) + i * 16 + lr;
            float ts = 0.f, tq = 0.f;
            #pragma unroll
            for (int w = 0; w < WC; w++) { ts += ssum[rb * WC + w]; tq += ssq[rb * WC + w]; }
            float mean = ts * (1.f / 256.f);
            float var = tq * (1.f / 256.f) - mean * mean;
            float inv = rsqrtf(var + 1e-5f);
            int row = ra0 + rb;
            #pragma unroll
            for (int j = 0; j < JN; j++) {
                int ncol = cb0 + wc * (JN * 16) + j * 16 + lg * 4;
                f32x4 gv = *(const f32x4*)&gw[ncol];
                f32x4 bv = *(const f32x4*)&bw[ncol];
                u16x4 ov;
                #pragma unroll
                for (int rr = 0; rr < 4; rr++)
                    ov[rr] = f2b((acc[i][j][rr] - mean) * inv * gv[rr] + bv[rr]);
                *(u16x4*)&C[(size_t)row * NN + ncol] = ov;
            }
        }
    }
}

// ---------------- classifier head ----------------
__global__ __launch_bounds__(256) void classifier(
    const unsigned short* __restrict__ xin,
    const float* __restrict__ Wc1, const float* __restrict__ bc1,
    const float* __restrict__ Wc2, const float* __restrict__ bc2,
    const float* __restrict__ Wc3, const float* __restrict__ bc3,
    float* __restrict__ out)
{
    __shared__ float w1[256][9];
    __shared__ float w2[64], b2s[8], w3[16], b3s[2], b1s[8];
    int t = threadIdx.x;
    #pragma unroll
    for (int i = 0; i < 8; i++) {
        int idx = t + i * 256;
        w1[idx >> 3][idx & 7] = Wc1[idx];
    }
    if (t < 64) w2[t] = Wc2[t];
    if (t < 16) w3[t] = Wc3[t];
    if (t < 8) { b2s[t] = bc2[t]; b1s[t] = bc1[t]; }
    if (t < 2) b3s[t] = bc3[t];
    __syncthreads();
    int g = t >> 3, m = t & 7;
    size_t row = (size_t)blockIdx.x * 32 + g;
    float z[8] = {0.f,0.f,0.f,0.f,0.f,0.f,0.f,0.f};
    const unsigned short* xr = xin + row * 256 + m * 32;
    #pragma unroll
    for (int cidx = 0; cidx < 4; cidx++) {
        u16x8 xv = *(const u16x8*)&xr[cidx * 8];
        #pragma unroll
        for (int e = 0; e < 8; e++) {
            float xf = b2f(xv[e]);
            int ei = m * 32 + cidx * 8 + e;
            #pragma unroll
            for (int j = 0; j < 8; j++) z[j] = fmaf(xf, w1[ei][j], z[j]);
        }
    }
    #pragma unroll
    for (int d = 1; d < 8; d <<= 1)
        #pragma unroll
        for (int j = 0; j < 8; j++) z[j] += __shfl_xor(z[j], d);
    float z1[8], z2[8];
    #pragma unroll
    for (int j = 0; j < 8; j++) z1[j] = tanhf(z[j] + b1s[j]);
    #pragma unroll
    for (int j2 = 0; j2 < 8; j2++) {
        float sacc = b2s[j2];
        #pragma unroll
        for (int j = 0; j < 8; j++) sacc = fmaf(z1[j], w2[j * 8 + j2], sacc);
        z2[j2] = tanhf(sacc);
    }
    if (m < 2) {
        float sacc = b3s[m];
        #pragma unroll
        for (int j = 0; j < 8; j++) sacc = fmaf(z2[j], w3[j * 2 + m], sacc);
        out[row * 2 + m] = 1.f / (1.f + __expf(-sacc));
    }
}

extern "C" void kernel_launch(void* const* d_in, const int* in_sizes, int n_in,
                              void* d_out, int out_size, void* d_ws, size_t ws_size,
                              hipStream_t stream) {
    const float* x        = (const float*)d_in[0];
    const float* q        = (const float*)d_in[1];
    const int*   positions= (const int*)d_in[2];
    const float* pos_emb  = (const float*)d_in[3];
    const float* Wq       = (const float*)d_in[4];
    const float* Wk       = (const float*)d_in[5];
    const float* Wv       = (const float*)d_in[6];
    const float* Wo       = (const float*)d_in[7];
    const float* bo       = (const float*)d_in[8];
    const float* g1       = (const float*)d_in[9];
    const float* b1       = (const float*)d_in[10];
    const float* g2       = (const float*)d_in[11];
    const float* b2       = (const float*)d_in[12];
    const float* Wf1      = (const float*)d_in[13];
    const float* bf1      = (const float*)d_in[14];
    const float* Wf2      = (const float*)d_in[15];
    const float* bf2      = (const float*)d_in[16];
    const float* Wc1      = (const float*)d_in[17];
    const float* bc1      = (const float*)d_in[18];
    const float* Wc2      = (const float*)d_in[19];
    const float* bc2      = (const float*)d_in[20];
    const float* Wc3      = (const float*)d_in[21];
    const float* bc3      = (const float*)d_in[22];
    float* out = (float*)d_out;

    const int R = 512 * 90;          // 46080 token rows
    char* ws = (char*)d_ws;
    size_t off = 0;
    auto alloc = [&](size_t bytes) -> void* {
        void* p = ws + off;
        off += (bytes + 255) & ~(size_t)255;
        return p;
    };
    unsigned short* cur = (unsigned short*)alloc((size_t)R * 256 * 2);
    unsigned short* qb  = (unsigned short*)alloc((size_t)R * 256 * 2);
    unsigned short* qho = (unsigned short*)alloc((size_t)R * 256 * 2);  // attn-out -> h (in-place LN)
    unsigned short* f1  = (unsigned short*)alloc((size_t)R * 1024 * 2);
    unsigned short* WoT = (unsigned short*)alloc((size_t)3 * 256 * 256 * 2);
    unsigned short* W1T = (unsigned short*)alloc((size_t)3 * 1024 * 256 * 2);
    unsigned short* W2T = (unsigned short*)alloc((size_t)3 * 256 * 1024 * 2);
    unsigned short* WTqkv = (unsigned short*)alloc((size_t)3 * 3 * 1024 * 2);

    for (int l = 0; l < 3; l++) {
        transpose_to_bf16<<<dim3(8, 8),  256, 0, stream>>>(Wo  + (size_t)l*256*256,  WoT + (size_t)l*256*256,  256, 256);
        transpose_to_bf16<<<dim3(8, 32), 256, 0, stream>>>(Wf1 + (size_t)l*256*1024, W1T + (size_t)l*1024*256, 256, 1024);
        transpose_to_bf16<<<dim3(32, 8), 256, 0, stream>>>(Wf2 + (size_t)l*1024*256, W2T + (size_t)l*256*1024, 1024, 256);
    }
    prep_wT<<<9, 256, 0, stream>>>(Wq, Wk, Wv, WTqkv);
    add_posemb<<<R, 256, 0, stream>>>(x, positions, pos_emb, cur);
    to_bf16_kernel<<<2048, 256, 0, stream>>>(q, qb, R * 256);

    for (int l = 0; l < 3; l++) {
        attn_kernel<<<512 * 8, 384, 0, stream>>>(cur, qb, WTqkv + (size_t)l * 3 * 1024, qho);
        // h = LN(attn_out @ Wo + bo + qb): in-place qho   (96x256 tile, 480 blocks)
        gemm5<6,4,1,4,0,1><<<dim3(480, 1), 256, 0, stream>>>(
            qho, WoT + (size_t)l*256*256, bo + l*256,
            qb, g1 + l*256, b1 + l*256, qho, R, 256, 256);
        // f1 = relu(h @ Wf1 + bf1)   (128x256 tile, 360x4 blocks)
        gemm5<4,8,2,2,1,0><<<dim3(360, 4), 256, 0, stream>>>(
            qho, W1T + (size_t)l*1024*256, bf1 + l*1024,
            nullptr, nullptr, nullptr, f1, R, 1024, 256);
        // cur = LN(f1 @ Wf2 + bf2 + h)   (96x256 tile, 480 blocks)
        gemm5<6,4,1,4,0,1><<<dim3(480, 1), 256, 0, stream>>>(
            f1, W2T + (size_t)l*256*1024, bf2 + l*256,
            qho, g2 + l*256, b2 + l*256, cur, R, 256, 1024);
    }
    classifier<<<R / 32, 256, 0, stream>>>(cur, Wc1, bc1, Wc2, bc2, Wc3, bc3, out);
}